// Round 12
// baseline (451.252 us; speedup 1.0000x reference)
//
#include <hip/hip_runtime.h>
#include <hip/hip_fp16.h>

typedef __attribute__((ext_vector_type(8))) short short8;
typedef __attribute__((ext_vector_type(4))) float f32x4;
typedef unsigned short u16;

__device__ __forceinline__ u16 f2bf(float f) {
    unsigned u = __float_as_uint(f);
    unsigned r = ((u >> 16) & 1) + 0x7FFFu;
    return (u16)((u + r) >> 16);
}

__device__ __forceinline__ void gload_lds16(const void* g, void* l) {
    __builtin_amdgcn_global_load_lds((const __attribute__((address_space(1))) unsigned int*)g,
                                     (__attribute__((address_space(3))) unsigned int*)l,
                                     16, 0, 0);
}

// packed fp16 ops (VOP3P)
__device__ __forceinline__ unsigned pk_fma(unsigned a, unsigned b, unsigned c) {
    unsigned d;
    asm("v_pk_fma_f16 %0, %1, %2, %3" : "=v"(d) : "v"(a), "v"(b), "v"(c));
    return d;
}
__device__ __forceinline__ unsigned pk_mul(unsigned a, unsigned b) {
    unsigned d;
    asm("v_pk_mul_f16 %0, %1, %2" : "=v"(d) : "v"(a), "v"(b));
    return d;
}
__device__ __forceinline__ unsigned pk_max(unsigned a, unsigned b) {
    unsigned d;
    asm("v_pk_max_f16 %0, %1, %2" : "=v"(d) : "v"(a), "v"(b));
    return d;
}
__device__ __forceinline__ unsigned pk_add(unsigned a, unsigned b) {
    unsigned d;
    asm("v_pk_add_f16 %0, %1, %2" : "=v"(d) : "v"(a), "v"(b));
    return d;
}

// ---------------- CSR build kernels ----------------

__global__ void k_count(const int* __restrict__ dst, int* __restrict__ cnt, int E) {
    int i = blockIdx.x * 256 + threadIdx.x;
    if (i < E) atomicAdd(&cnt[dst[i]], 1);
}

__global__ void k_scan1(const int* __restrict__ cnt, int* __restrict__ partial, int N) {
    __shared__ int sm[256];
    int idx = blockIdx.x * 256 + threadIdx.x;
    sm[threadIdx.x] = (idx < N) ? cnt[idx] : 0;
    __syncthreads();
    for (int s = 128; s > 0; s >>= 1) {
        if (threadIdx.x < s) sm[threadIdx.x] += sm[threadIdx.x + s];
        __syncthreads();
    }
    if (threadIdx.x == 0) partial[blockIdx.x] = sm[0];
}

__global__ void k_scan2(int* __restrict__ partial, int nb) {
    __shared__ int sm[512];
    int t = threadIdx.x;
    sm[t] = (t < nb) ? partial[t] : 0;
    __syncthreads();
    for (int off = 1; off < 512; off <<= 1) {
        int v = (t >= off) ? sm[t - off] : 0;
        __syncthreads();
        sm[t] += v;
        __syncthreads();
    }
    if (t < nb) partial[t] = (t == 0) ? 0 : sm[t - 1];  // exclusive
}

__global__ void k_scan3(const int* __restrict__ cnt, const int* __restrict__ partial,
                        int* __restrict__ row_off, int* __restrict__ cursor,
                        float* __restrict__ invdeg, int N, int E) {
    __shared__ int sm[256];
    int idx = blockIdx.x * 256 + threadIdx.x;
    int v = (idx < N) ? cnt[idx] : 0;
    sm[threadIdx.x] = v;
    __syncthreads();
    for (int off = 1; off < 256; off <<= 1) {
        int u = (threadIdx.x >= off) ? sm[threadIdx.x - off] : 0;
        __syncthreads();
        sm[threadIdx.x] += u;
        __syncthreads();
    }
    if (idx < N) {
        int excl = partial[blockIdx.x] + sm[threadIdx.x] - v;
        row_off[idx] = excl;
        cursor[idx] = excl;
        invdeg[idx] = 1.0f / (float)((v > 1) ? v : 1);
    }
    if (idx == 0) row_off[N] = E;
}

// scatter edge payload into CSR slots: {src, si_h2, di_h2, rv_h2} (broadcast half2)
__global__ void k_scatter(const int* __restrict__ dst, const int* __restrict__ src,
                          const float* __restrict__ sidx, const float* __restrict__ didx,
                          const float* __restrict__ rev,
                          int* __restrict__ cursor, int4* __restrict__ payload, int E) {
    int i = blockIdx.x * 256 + threadIdx.x;
    if (i < E) {
        int p = atomicAdd(&cursor[dst[i]], 1);
        unsigned hs = (unsigned)__half_as_ushort(__float2half_rn(sidx[i]));
        unsigned hd = (unsigned)__half_as_ushort(__float2half_rn(didx[i]));
        unsigned hr = (unsigned)__half_as_ushort(__float2half_rn(rev[i]));
        int4 v;
        v.x = src[i];
        v.y = (int)(hs * 0x10001u);
        v.z = (int)(hd * 0x10001u);
        v.w = (int)(hr * 0x10001u);
        payload[p] = v;
    }
}

// ---------------- embedding gather (bf16 out) ----------------

__global__ void k_emb(const int* __restrict__ gt, const float* __restrict__ emb,
                      u16* __restrict__ h0, int N) {
    int i = blockIdx.x * 256 + threadIdx.x;
    if (i < N * 64) {
        int n = i >> 6, f = i & 63;
        h0[i] = f2bf(emb[(gt[n] << 6) | f]);
    }
}

// ---------------- weight fp32 -> bf16 dense conversion ----------------

struct WDesc {
    const float* src[10];
    u16* dst[10];
    int scols[10];
    int dcols[10];
    int n[10];
};

__global__ void k_wconv(WDesc d) {
    int seg = blockIdx.y;
    int idx = blockIdx.x * 256 + threadIdx.x;
    if (idx < d.n[seg]) {
        int dc = d.dcols[seg];
        int r = idx / dc, c = idx % dc;
        d.dst[seg][idx] = f2bf(d.src[seg][r * d.scols[seg] + c]);
    }
}

// edge-weight cols of W1 as half2 pairs: W1h[c][j] = half2(W1[2j][fi+c], W1[2j+1][fi+c])
struct EDesc {
    const float* src[5];
    unsigned* dst[5];
    int ldw[5];
    int fi[5];
};

__global__ void k_wedge(EDesc d) {
    int l = blockIdx.x;
    int i = threadIdx.x;
    if (i < 192) {
        int c = i >> 6, j = i & 63;
        float a = d.src[l][(size_t)(2 * j) * d.ldw[l] + d.fi[l] + c];
        float b = d.src[l][(size_t)(2 * j + 1) * d.ldw[l] + d.fi[l] + c];
        unsigned lo = (unsigned)__half_as_ushort(__float2half_rn(a));
        unsigned hi = (unsigned)__half_as_ushort(__float2half_rn(b));
        d.dst[l][(c << 6) + j] = lo | (hi << 16);
    }
}

// ---------------- edge aggregation: 2 independent node-streams per wave ----------------
// Wave chunk split even/odd; streams alternate turns so one stream's payload->gather
// chain overlaps the other's compute. 4 edge-groups x 16 lanes, 8 feats/lane.
// Packed fp16 MLP + packed fp16 accumulation. row_off cached in lanes (shfl access).

__global__ __launch_bounds__(256)
void k_edge(int N,
            const int* __restrict__ row_off, const int4* __restrict__ payload,
            const u16* __restrict__ g,        // [N,128] fp16
            const unsigned* __restrict__ W1h, // [3][64] half2 pairs
            const float* __restrict__ invdeg,
            u16* __restrict__ hN)             // [N,128] bf16
{
    const int t = threadIdx.x;
    const int lane = t & 63;
    const int fl = lane & 15;
    const int eg = lane >> 4;
    const int wid = blockIdx.x * (blockDim.x >> 6) + (t >> 6);
    const int nwtot = gridDim.x * (blockDim.x >> 6);
    const int per = (N + nwtot - 1) / nwtot;
    const int n0 = wid * per;
    if (n0 >= N) return;
    const int n1 = (n0 + per < N) ? (n0 + per) : N;

    // lane l caches row_off[n0+l] (chunk spans per+1 <= 14 entries)
    int roi = n0 + lane;
    const int ro_l = row_off[(roi <= n1) ? roi : n1];

    const uint4 wa = *(const uint4*)&W1h[(fl << 2)];
    const uint4 wb = *(const uint4*)&W1h[64 + (fl << 2)];
    const uint4 wc = *(const uint4*)&W1h[128 + (fl << 2)];
    const unsigned c001 = ((unsigned)__half_as_ushort(__float2half_rn(0.01f))) * 0x10001u;

    int na, pa, ea, qa;
    int4 pla;
    uint4 gva;
    unsigned accA[4] = {0u, 0u, 0u, 0u};
    int nb_, pb, eb, qb;
    int4 plb;
    uint4 gvb;
    unsigned accB[4] = {0u, 0u, 0u, 0u};

    auto prime = [&](int n, int& p, int& e, int& q, int4& pl, uint4& gv) {
        const int idx = n - n0;
        const int b = __shfl(ro_l, idx, 64);
        e = __shfl(ro_l, idx + 1, 64);
        p = b + eg;
        q = (e - b + 3) >> 2;              // wave-uniform quad count (group 0 max)
        if (p < e) {
            pl = payload[p];
            gv = *(const uint4*)(g + ((size_t)pl.x << 7) + (fl << 3));
        }
    };

    auto quadf = [&](const int4& pl, const uint4& gv, unsigned* acc) {
        const unsigned si = (unsigned)pl.y;
        const unsigned di = (unsigned)pl.z;
        const unsigned rv = (unsigned)pl.w;
        unsigned v0 = pk_fma(wa.x, si, gv.x);
        unsigned v1 = pk_fma(wa.y, si, gv.y);
        unsigned v2 = pk_fma(wa.z, si, gv.z);
        unsigned v3 = pk_fma(wa.w, si, gv.w);
        v0 = pk_fma(wb.x, di, v0);
        v1 = pk_fma(wb.y, di, v1);
        v2 = pk_fma(wb.z, di, v2);
        v3 = pk_fma(wb.w, di, v3);
        v0 = pk_fma(wc.x, rv, v0);
        v1 = pk_fma(wc.y, rv, v1);
        v2 = pk_fma(wc.z, rv, v2);
        v3 = pk_fma(wc.w, rv, v3);
        v0 = pk_max(v0, pk_mul(v0, c001));
        v1 = pk_max(v1, pk_mul(v1, c001));
        v2 = pk_max(v2, pk_mul(v2, c001));
        v3 = pk_max(v3, pk_mul(v3, c001));
        acc[0] = pk_add(acc[0], v0);
        acc[1] = pk_add(acc[1], v1);
        acc[2] = pk_add(acc[2], v2);
        acc[3] = pk_add(acc[3], v3);
    };

    auto finishf = [&](int n, unsigned* acc) {
#pragma unroll
        for (int r = 0; r < 4; r++) {
            acc[r] = pk_add(acc[r], (unsigned)__shfl_xor((int)acc[r], 16, 64));
            acc[r] = pk_add(acc[r], (unsigned)__shfl_xor((int)acc[r], 32, 64));
        }
        if (eg == 0) {
            const float inv = invdeg[n];
            const float2 f0 = __half22float2(*(const __half2*)&acc[0]);
            const float2 f1 = __half22float2(*(const __half2*)&acc[1]);
            const float2 f2 = __half22float2(*(const __half2*)&acc[2]);
            const float2 f3 = __half22float2(*(const __half2*)&acc[3]);
            unsigned q0 = (unsigned)f2bf(f0.x * inv) | ((unsigned)f2bf(f0.y * inv) << 16);
            unsigned q1 = (unsigned)f2bf(f1.x * inv) | ((unsigned)f2bf(f1.y * inv) << 16);
            unsigned q2 = (unsigned)f2bf(f2.x * inv) | ((unsigned)f2bf(f2.y * inv) << 16);
            unsigned q3 = (unsigned)f2bf(f3.x * inv) | ((unsigned)f2bf(f3.y * inv) << 16);
            uint4 out = make_uint4(q0, q1, q2, q3);
            *(uint4*)(hN + ((size_t)n << 7) + (fl << 3)) = out;
        }
        acc[0] = acc[1] = acc[2] = acc[3] = 0u;
    };

    na = n0;
    prime(na, pa, ea, qa, pla, gva);
    nb_ = n0 + 1;
    bool doneB = (nb_ >= n1);
    if (!doneB) prime(nb_, pb, eb, qb, plb, gvb);
    bool doneA = false;

    while (!doneA || !doneB) {
        if (!doneA) {
            if (qa > 0) {
                if (pa < ea) quadf(pla, gva, accA);
                pa += 4;
                qa--;
                if (qa > 0 && pa < ea) {
                    pla = payload[pa];
                    gva = *(const uint4*)(g + ((size_t)pla.x << 7) + (fl << 3));
                }
            } else {
                finishf(na, accA);
                na += 2;
                if (na < n1) prime(na, pa, ea, qa, pla, gva);
                else doneA = true;
            }
        }
        if (!doneB) {
            if (qb > 0) {
                if (pb < eb) quadf(plb, gvb, accB);
                pb += 4;
                qb--;
                if (qb > 0 && pb < eb) {
                    plb = payload[pb];
                    gvb = *(const uint4*)(g + ((size_t)plb.x << 7) + (fl << 3));
                }
            } else {
                finishf(nb_, accB);
                nb_ += 2;
                if (nb_ < n1) prime(nb_, pb, eb, qb, plb, gvb);
                else doneB = true;
            }
        }
    }
}

// ---------------- bf16 MFMA GEMM, 512 threads = 8 waves (4M x 2N), staged LDS ----------------
// C[M,O] = [A1|A2] @ W[O,K]^T (+bias, act). Per wave: 32 rows x O/2 cols.
// FUSE: phase 2 computes g = h' @ Wg^T; h' re-read from GLOBAL (own block's L2-hot rows),
//       Wg re-staged into the dead Wlds region. OUTDT: 0=fp32, 1=bf16, 2=fp16.

template<int K, int O, int SPLIT, int BIAS, int RELU, int OUTDT, int FUSE>
__global__ __launch_bounds__(512, 4)
void k_gemm(int M,
            const u16* __restrict__ A1, int lda1,
            const u16* __restrict__ A2, int lda2,
            const u16* __restrict__ W,      // [O][K] bf16 dense
            const float* __restrict__ bias,
            void* __restrict__ Cout, int ldc,
            const u16* __restrict__ Wg,     // FUSE: next W1a [128][128] bf16
            u16* __restrict__ Gout)         // FUSE: g fp16 [M][128]
{
    constexpr int KP = K + 8;
    constexpr int HP = 136;
    constexpr int NF = O / 32;     // N-frags per wave (cols/wave = O/2)
    constexpr int WC = O / 2;
    __shared__ __align__(16) u16 Wlds[O * KP];       // phase1 W2; FUSE phase2: Wg at stride HP
    __shared__ __align__(16) u16 Atile[128 * 32];

    const int t = threadIdx.x;
    const int m0 = blockIdx.x * 128;
    const int w = t >> 6, l = t & 63;
    const int wm = w & 3, wn = w >> 2;
    const int lr = l & 15, lh = l >> 4;

    // stage W2 (L2-resident)
    for (int idx = t; idx < O * (K / 8); idx += 512) {
        int row = idx / (K / 8), ch = idx % (K / 8);
        uint4 v = *(const uint4*)(W + (size_t)row * K + ch * 8);
        *(uint4*)(&Wlds[row * KP + ch * 8]) = v;
    }

    f32x4 acc[2][NF];
#pragma unroll
    for (int mi = 0; mi < 2; mi++)
#pragma unroll
        for (int ni = 0; ni < NF; ni++) acc[mi][ni] = (f32x4){0.f, 0.f, 0.f, 0.f};

    __syncthreads();

    for (int kt = 0; kt < K / 32; ++kt) {
        const int k0 = kt * 32;
        const u16* Asrc;
        int lda, kof;
        if (k0 < SPLIT) { Asrc = A1; lda = lda1; kof = k0; }
        else            { Asrc = A2; lda = lda2; kof = k0 - SPLIT; }
        {
            int o = t * 16;                  // byte offset in Atile (512*16 = 8192)
            int row = o >> 6;
            int m = m0 + row;
            m = (m < M) ? m : (M - 1);
            gload_lds16(Asrc + (size_t)m * lda + kof + ((t & 3) << 3), (void*)(Atile + (o >> 1)));
        }
        __syncthreads();

        short8 a[2], b[NF];
#pragma unroll
        for (int mi = 0; mi < 2; mi++)
            a[mi] = *(const short8*)(Atile + (wm * 32 + mi * 16 + lr) * 32 + lh * 8);
#pragma unroll
        for (int ni = 0; ni < NF; ni++)
            b[ni] = *(const short8*)(Wlds + (size_t)(wn * WC + ni * 16 + lr) * KP + k0 + lh * 8);
#pragma unroll
        for (int mi = 0; mi < 2; mi++)
#pragma unroll
            for (int ni = 0; ni < NF; ni++)
                acc[mi][ni] = __builtin_amdgcn_mfma_f32_16x16x32_bf16(a[mi], b[ni], acc[mi][ni], 0, 0, 0);
        __syncthreads();
    }

    // FUSE: re-stage Wg into Wlds (dead after K-loop); overlaps epilogue VALU
    if (FUSE) {
        for (int idx = t; idx < 128 * 16; idx += 512) {
            int row = idx >> 4, ch = idx & 15;
            uint4 v = *(const uint4*)(Wg + (size_t)row * 128 + ch * 8);
            *(uint4*)(&Wlds[row * HP + ch * 8]) = v;
        }
    }

    // phase-1 epilogue (C/D map: row = lh*4 + i, col = lr per frag)
    float bv[NF];
#pragma unroll
    for (int ni = 0; ni < NF; ni++)
        bv[ni] = BIAS ? bias[wn * WC + ni * 16 + lr] : 0.f;
#pragma unroll
    for (int mi = 0; mi < 2; mi++) {
#pragma unroll
        for (int i = 0; i < 4; i++) {
            int row = m0 + wm * 32 + mi * 16 + lh * 4 + i;
            if (row < M) {
#pragma unroll
                for (int ni = 0; ni < NF; ni++) {
                    float v = acc[mi][ni][i] + bv[ni];
                    if (RELU) v = fmaxf(v, 0.f);
                    int col = wn * WC + ni * 16 + lr;
                    if (FUSE || OUTDT == 1) ((u16*)Cout)[(size_t)row * ldc + col] = f2bf(v);
                    else if (OUTDT == 2)    ((__half*)Cout)[(size_t)row * ldc + col] = __float2half(v);
                    else                    ((float*)Cout)[(size_t)row * ldc + col] = v;
                }
            }
        }
    }

    if (FUSE) {
        __syncthreads();   // drains vmcnt(0): h' stores visible in L2; Wg ds_writes done

        const u16* H = (const u16*)Cout;
        int hrow[2];
#pragma unroll
        for (int mi = 0; mi < 2; mi++) {
            int m = m0 + wm * 32 + mi * 16 + lr;
            hrow[mi] = (m < M) ? m : (M - 1);
        }

        f32x4 acc2[2][4];
#pragma unroll
        for (int mi = 0; mi < 2; mi++)
#pragma unroll
            for (int ni = 0; ni < 4; ni++) acc2[mi][ni] = (f32x4){0.f, 0.f, 0.f, 0.f};

#pragma unroll
        for (int kt = 0; kt < 4; ++kt) {
            const int k0 = kt * 32;
            short8 a[2], b[4];
#pragma unroll
            for (int mi = 0; mi < 2; mi++)
                a[mi] = *(const short8*)(H + (size_t)hrow[mi] * ldc + k0 + lh * 8);
#pragma unroll
            for (int ni = 0; ni < 4; ni++)
                b[ni] = *(const short8*)(Wlds + (size_t)(wn * 64 + ni * 16 + lr) * HP + k0 + lh * 8);
#pragma unroll
            for (int mi = 0; mi < 2; mi++)
#pragma unroll
                for (int ni = 0; ni < 4; ni++)
                    acc2[mi][ni] = __builtin_amdgcn_mfma_f32_16x16x32_bf16(a[mi], b[ni], acc2[mi][ni], 0, 0, 0);
        }

#pragma unroll
        for (int mi = 0; mi < 2; mi++) {
#pragma unroll
            for (int i = 0; i < 4; i++) {
                int row = m0 + wm * 32 + mi * 16 + lh * 4 + i;
                if (row < M) {
#pragma unroll
                    for (int ni = 0; ni < 4; ni++) {
                        int col = wn * 64 + ni * 16 + lr;
                        ((__half*)Gout)[(size_t)row * 128 + col] = __float2half(acc2[mi][ni][i]);
                    }
                }
            }
        }
    }
}

// ---------------- launcher ----------------

extern "C" void kernel_launch(void* const* d_in, const int* in_sizes, int n_in,
                              void* d_out, int out_size, void* d_ws, size_t ws_size,
                              hipStream_t stream)
{
    const int N = in_sizes[0];
    const int E = in_sizes[1];
    const int* gate = (const int*)d_in[0];
    const int* src = (const int*)d_in[1];
    const int* dst = (const int*)d_in[2];
    const float* sidx = (const float*)d_in[3];
    const float* didx = (const float*)d_in[4];
    const float* rev = (const float*)d_in[5];
    const float* emb = (const float*)d_in[6];
    const float* w1[5] = {(const float*)d_in[7], (const float*)d_in[10], (const float*)d_in[13],
                          (const float*)d_in[16], (const float*)d_in[19]};
    const float* w2[5] = {(const float*)d_in[8], (const float*)d_in[11], (const float*)d_in[14],
                          (const float*)d_in[17], (const float*)d_in[20]};
    const float* b2[5] = {(const float*)d_in[9], (const float*)d_in[12], (const float*)d_in[15],
                          (const float*)d_in[18], (const float*)d_in[21]};

    char* ws = (char*)d_ws;
    size_t off = 0;
    auto alloc = [&](size_t bytes) {
        void* p = ws + off;
        off = (off + bytes + 255) & ~(size_t)255;
        return p;
    };
    u16* hb0 = (u16*)alloc((size_t)N * 128 * 2);
    u16* hb1 = (u16*)alloc((size_t)N * 128 * 2);
    u16* hN = (u16*)alloc((size_t)N * 128 * 2);
    u16* g = (u16*)alloc((size_t)N * 128 * 2);        // fp16
    int* cnt = (int*)alloc((size_t)N * 4);
    int* row_off = (int*)alloc((size_t)(N + 1) * 4);
    int* cursor = (int*)alloc((size_t)N * 4);
    int4* payload = (int4*)alloc((size_t)E * 16);
    int* partial = (int*)alloc(512 * 4);
    float* invd = (float*)alloc((size_t)N * 4);
    unsigned* w1h = (unsigned*)alloc(5 * 192 * 4);
    u16* w1b[5];
    u16* w2b[5];
    const int fis[5] = {64, 128, 128, 128, 128};
    for (int i = 0; i < 5; i++) w1b[i] = (u16*)alloc((size_t)128 * fis[i] * 2);
    for (int i = 0; i < 5; i++) {
        int fo = (i == 4) ? 64 : 128;
        w2b[i] = (u16*)alloc((size_t)fo * (fis[i] + 128) * 2);
    }

    WDesc wd;
    for (int i = 0; i < 5; i++) {
        wd.src[i] = w1[i]; wd.dst[i] = w1b[i];
        wd.scols[i] = fis[i] + 3; wd.dcols[i] = fis[i]; wd.n[i] = 128 * fis[i];
        int fo = (i == 4) ? 64 : 128;
        wd.src[5 + i] = w2[i]; wd.dst[5 + i] = w2b[i];
        wd.scols[5 + i] = fis[i] + 128; wd.dcols[5 + i] = fis[i] + 128;
        wd.n[5 + i] = fo * (fis[i] + 128);
    }
    k_wconv<<<dim3(128, 10), dim3(256), 0, stream>>>(wd);

    EDesc ed;
    for (int i = 0; i < 5; i++) {
        ed.src[i] = w1[i];
        ed.dst[i] = w1h + i * 192;
        ed.ldw[i] = fis[i] + 3;
        ed.fi[i] = fis[i];
    }
    k_wedge<<<dim3(5), dim3(192), 0, stream>>>(ed);

    hipMemsetAsync(cnt, 0, (size_t)N * 4, stream);
    k_count<<<dim3((E + 255) / 256), dim3(256), 0, stream>>>(dst, cnt, E);
    const int nb = (N + 255) / 256;
    k_scan1<<<dim3(nb), dim3(256), 0, stream>>>(cnt, partial, N);
    k_scan2<<<dim3(1), dim3(512), 0, stream>>>(partial, nb);
    k_scan3<<<dim3(nb), dim3(256), 0, stream>>>(cnt, partial, row_off, cursor, invd, N, E);
    k_scatter<<<dim3((E + 255) / 256), dim3(256), 0, stream>>>(dst, src, sidx, didx, rev, cursor, payload, E);
    k_emb<<<dim3((N * 64 + 255) / 256), dim3(256), 0, stream>>>(gate, emb, hb0, N);

    const int gg = (N + 127) / 128;
    const int eb = 2048;

    // ---- layer 1 (fi=64): g1 standalone, then fused W2+g2 ----
    k_gemm<64, 128, 64, 0, 0, 2, 0><<<dim3(gg), dim3(512), 0, stream>>>(
        N, hb0, 64, (const u16*)nullptr, 0, w1b[0], (const float*)nullptr, g, 128,
        (const u16*)nullptr, (u16*)nullptr);
    k_edge<<<dim3(eb), dim3(256), 0, stream>>>(N, row_off, payload, g, w1h + 0 * 192, invd, hN);
    k_gemm<192, 128, 64, 1, 1, 1, 1><<<dim3(gg), dim3(512), 0, stream>>>(
        N, hb0, 64, hN, 128, w2b[0], b2[0], hb1, 128, w1b[1], g);

    // ---- layers 2..4: fused W2 + next g ----
    u16* hcur = hb1;
    u16* hnxt = hb0;
    for (int l = 1; l < 4; ++l) {
        k_edge<<<dim3(eb), dim3(256), 0, stream>>>(N, row_off, payload, g, w1h + l * 192, invd, hN);
        k_gemm<256, 128, 128, 1, 1, 1, 1><<<dim3(gg), dim3(512), 0, stream>>>(
            N, hcur, 128, hN, 128, w2b[l], b2[l], hnxt, 128, w1b[l + 1], g);
        u16* tmp = hcur; hcur = hnxt; hnxt = tmp;
    }

    // ---- layer 5: edge + final W2 (out 64 fp32, no relu) ----
    k_edge<<<dim3(eb), dim3(256), 0, stream>>>(N, row_off, payload, g, w1h + 4 * 192, invd, hN);
    k_gemm<256, 64, 128, 1, 0, 0, 0><<<dim3(gg), dim3(512), 0, stream>>>(
        N, hcur, 128, hN, 128, w2b[4], b2[4], (float*)d_out, 64,
        (const u16*)nullptr, (u16*)nullptr);
}

// Round 13
// 446.278 us; speedup vs baseline: 1.0111x; 1.0111x over previous
//
#include <hip/hip_runtime.h>
#include <hip/hip_fp16.h>

typedef __attribute__((ext_vector_type(8))) short short8;
typedef __attribute__((ext_vector_type(4))) float f32x4;
typedef unsigned short u16;

__device__ __forceinline__ u16 f2bf(float f) {
    unsigned u = __float_as_uint(f);
    unsigned r = ((u >> 16) & 1) + 0x7FFFu;
    return (u16)((u + r) >> 16);
}

__device__ __forceinline__ void gload_lds16(const void* g, void* l) {
    __builtin_amdgcn_global_load_lds((const __attribute__((address_space(1))) unsigned int*)g,
                                     (__attribute__((address_space(3))) unsigned int*)l,
                                     16, 0, 0);
}

// packed fp16 ops (VOP3P)
__device__ __forceinline__ unsigned pk_fma(unsigned a, unsigned b, unsigned c) {
    unsigned d;
    asm("v_pk_fma_f16 %0, %1, %2, %3" : "=v"(d) : "v"(a), "v"(b), "v"(c));
    return d;
}
__device__ __forceinline__ unsigned pk_mul(unsigned a, unsigned b) {
    unsigned d;
    asm("v_pk_mul_f16 %0, %1, %2" : "=v"(d) : "v"(a), "v"(b));
    return d;
}
__device__ __forceinline__ unsigned pk_max(unsigned a, unsigned b) {
    unsigned d;
    asm("v_pk_max_f16 %0, %1, %2" : "=v"(d) : "v"(a), "v"(b));
    return d;
}

// ---------------- CSR build kernels ----------------

__global__ void k_count(const int* __restrict__ dst, int* __restrict__ cnt, int E) {
    int i = blockIdx.x * 256 + threadIdx.x;
    if (i < E) atomicAdd(&cnt[dst[i]], 1);
}

__global__ void k_scan1(const int* __restrict__ cnt, int* __restrict__ partial, int N) {
    __shared__ int sm[256];
    int idx = blockIdx.x * 256 + threadIdx.x;
    sm[threadIdx.x] = (idx < N) ? cnt[idx] : 0;
    __syncthreads();
    for (int s = 128; s > 0; s >>= 1) {
        if (threadIdx.x < s) sm[threadIdx.x] += sm[threadIdx.x + s];
        __syncthreads();
    }
    if (threadIdx.x == 0) partial[blockIdx.x] = sm[0];
}

__global__ void k_scan2(int* __restrict__ partial, int nb) {
    __shared__ int sm[512];
    int t = threadIdx.x;
    sm[t] = (t < nb) ? partial[t] : 0;
    __syncthreads();
    for (int off = 1; off < 512; off <<= 1) {
        int v = (t >= off) ? sm[t - off] : 0;
        __syncthreads();
        sm[t] += v;
        __syncthreads();
    }
    if (t < nb) partial[t] = (t == 0) ? 0 : sm[t - 1];  // exclusive
}

__global__ void k_scan3(const int* __restrict__ cnt, const int* __restrict__ partial,
                        int* __restrict__ row_off, int* __restrict__ cursor,
                        float* __restrict__ invdeg, int N, int E) {
    __shared__ int sm[256];
    int idx = blockIdx.x * 256 + threadIdx.x;
    int v = (idx < N) ? cnt[idx] : 0;
    sm[threadIdx.x] = v;
    __syncthreads();
    for (int off = 1; off < 256; off <<= 1) {
        int u = (threadIdx.x >= off) ? sm[threadIdx.x - off] : 0;
        __syncthreads();
        sm[threadIdx.x] += u;
        __syncthreads();
    }
    if (idx < N) {
        int excl = partial[blockIdx.x] + sm[threadIdx.x] - v;
        row_off[idx] = excl;
        cursor[idx] = excl;
        invdeg[idx] = 1.0f / (float)((v > 1) ? v : 1);
    }
    if (idx == 0) row_off[N] = E;
}

// scatter edge payload into CSR slots: {src, si_h2, di_h2, rv_h2} (broadcast half2)
__global__ void k_scatter(const int* __restrict__ dst, const int* __restrict__ src,
                          const float* __restrict__ sidx, const float* __restrict__ didx,
                          const float* __restrict__ rev,
                          int* __restrict__ cursor, int4* __restrict__ payload, int E) {
    int i = blockIdx.x * 256 + threadIdx.x;
    if (i < E) {
        int p = atomicAdd(&cursor[dst[i]], 1);
        unsigned hs = (unsigned)__half_as_ushort(__float2half_rn(sidx[i]));
        unsigned hd = (unsigned)__half_as_ushort(__float2half_rn(didx[i]));
        unsigned hr = (unsigned)__half_as_ushort(__float2half_rn(rev[i]));
        int4 v;
        v.x = src[i];
        v.y = (int)(hs * 0x10001u);
        v.z = (int)(hd * 0x10001u);
        v.w = (int)(hr * 0x10001u);
        payload[p] = v;
    }
}

// ---------------- layer-1 tables: T0 = bf16(emb) [64][64], T1 = emb @ W1a^T fp16 [64][128] ----------------

__global__ void k_tab(const float* __restrict__ emb, const float* __restrict__ w1,
                      u16* __restrict__ T0, u16* __restrict__ T1) {
    int t = threadIdx.x;
    for (int i = t; i < 64 * 64; i += 256) T0[i] = f2bf(emb[i]);
    for (int i = t; i < 64 * 128; i += 256) {
        int ty = i >> 7, j = i & 127;
        float acc = 0.f;
#pragma unroll 8
        for (int k = 0; k < 64; k++)
            acc = fmaf(emb[ty * 64 + k], w1[j * 67 + k], acc);
        T1[i] = (u16)__half_as_ushort(__float2half_rn(acc));
    }
}

// gather tables per node: h0 (bf16, 8 uint4) + g (fp16, 16 uint4), coalesced row copies
__global__ void k_emb2(const int* __restrict__ gt, const uint4* __restrict__ T0,
                       const uint4* __restrict__ T1, uint4* __restrict__ h0,
                       uint4* __restrict__ g, int N) {
    int i = blockIdx.x * 256 + threadIdx.x;
    if (i < N * 16) {
        int n = i >> 4, c = i & 15;
        int ty = gt[n];
        g[i] = T1[ty * 16 + c];
        if (c < 8) h0[n * 8 + c] = T0[ty * 8 + c];
    }
}

// ---------------- weight fp32 -> bf16 dense conversion ----------------

struct WDesc {
    const float* src[10];
    u16* dst[10];
    int scols[10];
    int dcols[10];
    int n[10];
};

__global__ void k_wconv(WDesc d) {
    int seg = blockIdx.y;
    int idx = blockIdx.x * 256 + threadIdx.x;
    if (idx < d.n[seg]) {
        int dc = d.dcols[seg];
        int r = idx / dc, c = idx % dc;
        d.dst[seg][idx] = f2bf(d.src[seg][r * d.scols[seg] + c]);
    }
}

// edge-weight cols of W1 as half2 pairs: W1h[c][j] = half2(W1[2j][fi+c], W1[2j+1][fi+c])
struct EDesc {
    const float* src[5];
    unsigned* dst[5];
    int ldw[5];
    int fi[5];
};

__global__ void k_wedge(EDesc d) {
    int l = blockIdx.x;
    int i = threadIdx.x;
    if (i < 192) {
        int c = i >> 6, j = i & 63;
        float a = d.src[l][(size_t)(2 * j) * d.ldw[l] + d.fi[l] + c];
        float b = d.src[l][(size_t)(2 * j + 1) * d.ldw[l] + d.fi[l] + c];
        unsigned lo = (unsigned)__half_as_ushort(__float2half_rn(a));
        unsigned hi = (unsigned)__half_as_ushort(__float2half_rn(b));
        d.dst[l][(c << 6) + j] = lo | (hi << 16);
    }
}

// ---------------- edge aggregation: grid-stride chunked waves, packed fp16 MLP ----------------
// (round-8 structure — fastest measured; rounds 4/5/12 restructures all regressed)

__global__ __launch_bounds__(256)
void k_edge(int N,
            const int* __restrict__ row_off, const int4* __restrict__ payload,
            const u16* __restrict__ g,        // [N,128] fp16
            const unsigned* __restrict__ W1h, // [3][64] half2 pairs
            const float* __restrict__ invdeg,
            u16* __restrict__ hN)             // [N,128] bf16
{
    const int t = threadIdx.x;
    const int lane = t & 63;
    const int fl = lane & 15;
    const int eg = lane >> 4;
    const int wid = blockIdx.x * (blockDim.x >> 6) + (t >> 6);
    const int nwtot = gridDim.x * (blockDim.x >> 6);
    const int per = (N + nwtot - 1) / nwtot;
    const int n0 = wid * per;
    if (n0 >= N) return;
    const int n1 = (n0 + per < N) ? (n0 + per) : N;

    const uint4 wa = *(const uint4*)&W1h[(fl << 2)];
    const uint4 wb = *(const uint4*)&W1h[64 + (fl << 2)];
    const uint4 wc = *(const uint4*)&W1h[128 + (fl << 2)];
    const unsigned c001 = ((unsigned)__half_as_ushort(__float2half_rn(0.01f))) * 0x10001u;

    int beg = row_off[n0];
    for (int n = n0; n < n1; ++n) {
        const int end = row_off[n + 1];
        float acc[8] = {0.f, 0.f, 0.f, 0.f, 0.f, 0.f, 0.f, 0.f};

        int p = beg + eg;
        int4 pl;
        if (p < end) pl = payload[p];
        while (p < end) {
            const int pn = p + 4;
            int4 plN = pl;
            if (pn < end) plN = payload[pn];
            const uint4 gv = *(const uint4*)(g + ((size_t)pl.x << 7) + (fl << 3));
            const unsigned si = (unsigned)pl.y;
            const unsigned di = (unsigned)pl.z;
            const unsigned rv = (unsigned)pl.w;
            unsigned v0 = pk_fma(wa.x, si, gv.x);
            unsigned v1 = pk_fma(wa.y, si, gv.y);
            unsigned v2 = pk_fma(wa.z, si, gv.z);
            unsigned v3 = pk_fma(wa.w, si, gv.w);
            v0 = pk_fma(wb.x, di, v0);
            v1 = pk_fma(wb.y, di, v1);
            v2 = pk_fma(wb.z, di, v2);
            v3 = pk_fma(wb.w, di, v3);
            v0 = pk_fma(wc.x, rv, v0);
            v1 = pk_fma(wc.y, rv, v1);
            v2 = pk_fma(wc.z, rv, v2);
            v3 = pk_fma(wc.w, rv, v3);
            v0 = pk_max(v0, pk_mul(v0, c001));
            v1 = pk_max(v1, pk_mul(v1, c001));
            v2 = pk_max(v2, pk_mul(v2, c001));
            v3 = pk_max(v3, pk_mul(v3, c001));
            const float2 f0 = __half22float2(*(const __half2*)&v0);
            const float2 f1 = __half22float2(*(const __half2*)&v1);
            const float2 f2 = __half22float2(*(const __half2*)&v2);
            const float2 f3 = __half22float2(*(const __half2*)&v3);
            acc[0] += f0.x; acc[1] += f0.y;
            acc[2] += f1.x; acc[3] += f1.y;
            acc[4] += f2.x; acc[5] += f2.y;
            acc[6] += f3.x; acc[7] += f3.y;
            p = pn;
            pl = plN;
        }

#pragma unroll
        for (int r = 0; r < 8; r++) {
            acc[r] += __shfl_xor(acc[r], 16, 64);
            acc[r] += __shfl_xor(acc[r], 32, 64);
        }

        if (eg == 0) {
            const float inv = invdeg[n];
            unsigned q0 = (unsigned)f2bf(acc[0] * inv) | ((unsigned)f2bf(acc[1] * inv) << 16);
            unsigned q1 = (unsigned)f2bf(acc[2] * inv) | ((unsigned)f2bf(acc[3] * inv) << 16);
            unsigned q2 = (unsigned)f2bf(acc[4] * inv) | ((unsigned)f2bf(acc[5] * inv) << 16);
            unsigned q3 = (unsigned)f2bf(acc[6] * inv) | ((unsigned)f2bf(acc[7] * inv) << 16);
            uint4 out = make_uint4(q0, q1, q2, q3);
            *(uint4*)(hN + ((size_t)n << 7) + (fl << 3)) = out;
        }
        beg = end;
    }
}

// ---------------- bf16 MFMA GEMM, 512 threads = 8 waves (4M x 2N), staged LDS ----------------
// C[M,O] = [A1|A2] @ W[O,K]^T (+bias, act). Per wave: 32 rows x O/2 cols.
// FUSE: phase 2 computes g = h' @ Wg^T; h' re-read from GLOBAL (own block's L2-hot rows),
//       Wg re-staged into the dead Wlds region. OUTDT: 0=fp32, 1=bf16, 2=fp16.

template<int K, int O, int SPLIT, int BIAS, int RELU, int OUTDT, int FUSE>
__global__ __launch_bounds__(512, 4)
void k_gemm(int M,
            const u16* __restrict__ A1, int lda1,
            const u16* __restrict__ A2, int lda2,
            const u16* __restrict__ W,      // [O][K] bf16 dense
            const float* __restrict__ bias,
            void* __restrict__ Cout, int ldc,
            const u16* __restrict__ Wg,     // FUSE: next W1a [128][128] bf16
            u16* __restrict__ Gout)         // FUSE: g fp16 [M][128]
{
    constexpr int KP = K + 8;
    constexpr int HP = 136;
    constexpr int NF = O / 32;     // N-frags per wave (cols/wave = O/2)
    constexpr int WC = O / 2;
    __shared__ __align__(16) u16 Wlds[O * KP];       // phase1 W2; FUSE phase2: Wg at stride HP
    __shared__ __align__(16) u16 Atile[128 * 32];

    const int t = threadIdx.x;
    const int m0 = blockIdx.x * 128;
    const int w = t >> 6, l = t & 63;
    const int wm = w & 3, wn = w >> 2;
    const int lr = l & 15, lh = l >> 4;

    // stage W2 (L2-resident)
    for (int idx = t; idx < O * (K / 8); idx += 512) {
        int row = idx / (K / 8), ch = idx % (K / 8);
        uint4 v = *(const uint4*)(W + (size_t)row * K + ch * 8);
        *(uint4*)(&Wlds[row * KP + ch * 8]) = v;
    }

    f32x4 acc[2][NF];
#pragma unroll
    for (int mi = 0; mi < 2; mi++)
#pragma unroll
        for (int ni = 0; ni < NF; ni++) acc[mi][ni] = (f32x4){0.f, 0.f, 0.f, 0.f};

    __syncthreads();

    for (int kt = 0; kt < K / 32; ++kt) {
        const int k0 = kt * 32;
        const u16* Asrc;
        int lda, kof;
        if (k0 < SPLIT) { Asrc = A1; lda = lda1; kof = k0; }
        else            { Asrc = A2; lda = lda2; kof = k0 - SPLIT; }
        {
            int o = t * 16;                  // byte offset in Atile (512*16 = 8192)
            int row = o >> 6;
            int m = m0 + row;
            m = (m < M) ? m : (M - 1);
            gload_lds16(Asrc + (size_t)m * lda + kof + ((t & 3) << 3), (void*)(Atile + (o >> 1)));
        }
        __syncthreads();

        short8 a[2], b[NF];
#pragma unroll
        for (int mi = 0; mi < 2; mi++)
            a[mi] = *(const short8*)(Atile + (wm * 32 + mi * 16 + lr) * 32 + lh * 8);
#pragma unroll
        for (int ni = 0; ni < NF; ni++)
            b[ni] = *(const short8*)(Wlds + (size_t)(wn * WC + ni * 16 + lr) * KP + k0 + lh * 8);
#pragma unroll
        for (int mi = 0; mi < 2; mi++)
#pragma unroll
            for (int ni = 0; ni < NF; ni++)
                acc[mi][ni] = __builtin_amdgcn_mfma_f32_16x16x32_bf16(a[mi], b[ni], acc[mi][ni], 0, 0, 0);
        __syncthreads();
    }

    // FUSE: re-stage Wg into Wlds (dead after K-loop); overlaps epilogue VALU
    if (FUSE) {
        for (int idx = t; idx < 128 * 16; idx += 512) {
            int row = idx >> 4, ch = idx & 15;
            uint4 v = *(const uint4*)(Wg + (size_t)row * 128 + ch * 8);
            *(uint4*)(&Wlds[row * HP + ch * 8]) = v;
        }
    }

    // phase-1 epilogue (C/D map: row = lh*4 + i, col = lr per frag)
    float bv[NF];
#pragma unroll
    for (int ni = 0; ni < NF; ni++)
        bv[ni] = BIAS ? bias[wn * WC + ni * 16 + lr] : 0.f;
#pragma unroll
    for (int mi = 0; mi < 2; mi++) {
#pragma unroll
        for (int i = 0; i < 4; i++) {
            int row = m0 + wm * 32 + mi * 16 + lh * 4 + i;
            if (row < M) {
#pragma unroll
                for (int ni = 0; ni < NF; ni++) {
                    float v = acc[mi][ni][i] + bv[ni];
                    if (RELU) v = fmaxf(v, 0.f);
                    int col = wn * WC + ni * 16 + lr;
                    if (FUSE || OUTDT == 1) ((u16*)Cout)[(size_t)row * ldc + col] = f2bf(v);
                    else if (OUTDT == 2)    ((__half*)Cout)[(size_t)row * ldc + col] = __float2half(v);
                    else                    ((float*)Cout)[(size_t)row * ldc + col] = v;
                }
            }
        }
    }

    if (FUSE) {
        __syncthreads();   // drains vmcnt(0): h' stores visible in L2; Wg ds_writes done

        const u16* H = (const u16*)Cout;
        int hrow[2];
#pragma unroll
        for (int mi = 0; mi < 2; mi++) {
            int m = m0 + wm * 32 + mi * 16 + lr;
            hrow[mi] = (m < M) ? m : (M - 1);
        }

        f32x4 acc2[2][4];
#pragma unroll
        for (int mi = 0; mi < 2; mi++)
#pragma unroll
            for (int ni = 0; ni < 4; ni++) acc2[mi][ni] = (f32x4){0.f, 0.f, 0.f, 0.f};

#pragma unroll
        for (int kt = 0; kt < 4; ++kt) {
            const int k0 = kt * 32;
            short8 a[2], b[4];
#pragma unroll
            for (int mi = 0; mi < 2; mi++)
                a[mi] = *(const short8*)(H + (size_t)hrow[mi] * ldc + k0 + lh * 8);
#pragma unroll
            for (int ni = 0; ni < 4; ni++)
                b[ni] = *(const short8*)(Wlds + (size_t)(wn * 64 + ni * 16 + lr) * HP + k0 + lh * 8);
#pragma unroll
            for (int mi = 0; mi < 2; mi++)
#pragma unroll
                for (int ni = 0; ni < 4; ni++)
                    acc2[mi][ni] = __builtin_amdgcn_mfma_f32_16x16x32_bf16(a[mi], b[ni], acc2[mi][ni], 0, 0, 0);
        }

#pragma unroll
        for (int mi = 0; mi < 2; mi++) {
#pragma unroll
            for (int i = 0; i < 4; i++) {
                int row = m0 + wm * 32 + mi * 16 + lh * 4 + i;
                if (row < M) {
#pragma unroll
                    for (int ni = 0; ni < 4; ni++) {
                        int col = wn * 64 + ni * 16 + lr;
                        ((__half*)Gout)[(size_t)row * 128 + col] = __float2half(acc2[mi][ni][i]);
                    }
                }
            }
        }
    }
}

// ---------------- launcher ----------------

extern "C" void kernel_launch(void* const* d_in, const int* in_sizes, int n_in,
                              void* d_out, int out_size, void* d_ws, size_t ws_size,
                              hipStream_t stream)
{
    const int N = in_sizes[0];
    const int E = in_sizes[1];
    const int* gate = (const int*)d_in[0];
    const int* src = (const int*)d_in[1];
    const int* dst = (const int*)d_in[2];
    const float* sidx = (const float*)d_in[3];
    const float* didx = (const float*)d_in[4];
    const float* rev = (const float*)d_in[5];
    const float* emb = (const float*)d_in[6];
    const float* w1[5] = {(const float*)d_in[7], (const float*)d_in[10], (const float*)d_in[13],
                          (const float*)d_in[16], (const float*)d_in[19]};
    const float* w2[5] = {(const float*)d_in[8], (const float*)d_in[11], (const float*)d_in[14],
                          (const float*)d_in[17], (const float*)d_in[20]};
    const float* b2[5] = {(const float*)d_in[9], (const float*)d_in[12], (const float*)d_in[15],
                          (const float*)d_in[18], (const float*)d_in[21]};

    char* ws = (char*)d_ws;
    size_t off = 0;
    auto alloc = [&](size_t bytes) {
        void* p = ws + off;
        off = (off + bytes + 255) & ~(size_t)255;
        return p;
    };
    u16* hb0 = (u16*)alloc((size_t)N * 128 * 2);
    u16* hb1 = (u16*)alloc((size_t)N * 128 * 2);
    u16* hN = (u16*)alloc((size_t)N * 128 * 2);
    u16* g = (u16*)alloc((size_t)N * 128 * 2);        // fp16
    int* cnt = (int*)alloc((size_t)N * 4);
    int* row_off = (int*)alloc((size_t)(N + 1) * 4);
    int* cursor = (int*)alloc((size_t)N * 4);
    int4* payload = (int4*)alloc((size_t)E * 16);
    int* partial = (int*)alloc(512 * 4);
    float* invd = (float*)alloc((size_t)N * 4);
    unsigned* w1h = (unsigned*)alloc(5 * 192 * 4);
    u16* T0 = (u16*)alloc(64 * 64 * 2);
    u16* T1 = (u16*)alloc(64 * 128 * 2);
    u16* w1b[5];
    u16* w2b[5];
    const int fis[5] = {64, 128, 128, 128, 128};
    for (int i = 0; i < 5; i++) w1b[i] = (u16*)alloc((size_t)128 * fis[i] * 2);
    for (int i = 0; i < 5; i++) {
        int fo = (i == 4) ? 64 : 128;
        w2b[i] = (u16*)alloc((size_t)fo * (fis[i] + 128) * 2);
    }

    WDesc wd;
    for (int i = 0; i < 5; i++) {
        wd.src[i] = w1[i]; wd.dst[i] = w1b[i];
        wd.scols[i] = fis[i] + 3; wd.dcols[i] = fis[i]; wd.n[i] = 128 * fis[i];
        int fo = (i == 4) ? 64 : 128;
        wd.src[5 + i] = w2[i]; wd.dst[5 + i] = w2b[i];
        wd.scols[5 + i] = fis[i] + 128; wd.dcols[5 + i] = fis[i] + 128;
        wd.n[5 + i] = fo * (fis[i] + 128);
    }
    k_wconv<<<dim3(128, 10), dim3(256), 0, stream>>>(wd);

    EDesc ed;
    for (int i = 0; i < 5; i++) {
        ed.src[i] = w1[i];
        ed.dst[i] = w1h + i * 192;
        ed.ldw[i] = fis[i] + 3;
        ed.fi[i] = fis[i];
    }
    k_wedge<<<dim3(5), dim3(192), 0, stream>>>(ed);
    k_tab<<<dim3(1), dim3(256), 0, stream>>>(emb, w1[0], T0, T1);

    hipMemsetAsync(cnt, 0, (size_t)N * 4, stream);
    k_count<<<dim3((E + 255) / 256), dim3(256), 0, stream>>>(dst, cnt, E);
    const int nb = (N + 255) / 256;
    k_scan1<<<dim3(nb), dim3(256), 0, stream>>>(cnt, partial, N);
    k_scan2<<<dim3(1), dim3(512), 0, stream>>>(partial, nb);
    k_scan3<<<dim3(nb), dim3(256), 0, stream>>>(cnt, partial, row_off, cursor, invd, N, E);
    k_scatter<<<dim3((E + 255) / 256), dim3(256), 0, stream>>>(dst, src, sidx, didx, rev, cursor, payload, E);
    // layer-1 h0 + g via table gather (replaces k_emb + standalone g1 GEMM)
    k_emb2<<<dim3((N * 16 + 255) / 256), dim3(256), 0, stream>>>(
        gate, (const uint4*)T0, (const uint4*)T1, (uint4*)hb0, (uint4*)g, N);

    const int gg = (N + 127) / 128;
    const int eb = 2048;

    // ---- layer 1 (fi=64): edge + fused W2+g2 ----
    k_edge<<<dim3(eb), dim3(256), 0, stream>>>(N, row_off, payload, g, w1h + 0 * 192, invd, hN);
    k_gemm<192, 128, 64, 1, 1, 1, 1><<<dim3(gg), dim3(512), 0, stream>>>(
        N, hb0, 64, hN, 128, w2b[0], b2[0], hb1, 128, w1b[1], g);

    // ---- layers 2..4: fused W2 + next g ----
    u16* hcur = hb1;
    u16* hnxt = hb0;
    for (int l = 1; l < 4; ++l) {
        k_edge<<<dim3(eb), dim3(256), 0, stream>>>(N, row_off, payload, g, w1h + l * 192, invd, hN);
        k_gemm<256, 128, 128, 1, 1, 1, 1><<<dim3(gg), dim3(512), 0, stream>>>(
            N, hcur, 128, hN, 128, w2b[l], b2[l], hnxt, 128, w1b[l + 1], g);
        u16* tmp = hcur; hcur = hnxt; hnxt = tmp;
    }

    // ---- layer 5: edge + final W2 (out 64 fp32, no relu) ----
    k_edge<<<dim3(eb), dim3(256), 0, stream>>>(N, row_off, payload, g, w1h + 4 * 192, invd, hN);
    k_gemm<256, 64, 128, 1, 0, 0, 0><<<dim3(gg), dim3(512), 0, stream>>>(
        N, hcur, 128, hN, 128, w2b[4], b2[4], (float*)d_out, 64,
        (const u16*)nullptr, (u16*)nullptr);
}

// Round 14
// 400.379 us; speedup vs baseline: 1.1271x; 1.1146x over previous
//
#include <hip/hip_runtime.h>
#include <hip/hip_fp16.h>

typedef __attribute__((ext_vector_type(8))) short short8;
typedef __attribute__((ext_vector_type(4))) float f32x4;
typedef unsigned short u16;

__device__ __forceinline__ u16 f2bf(float f) {
    unsigned u = __float_as_uint(f);
    unsigned r = ((u >> 16) & 1) + 0x7FFFu;
    return (u16)((u + r) >> 16);
}

__device__ __forceinline__ void gload_lds16(const void* g, void* l) {
    __builtin_amdgcn_global_load_lds((const __attribute__((address_space(1))) unsigned int*)g,
                                     (__attribute__((address_space(3))) unsigned int*)l,
                                     16, 0, 0);
}

// packed fp16 ops (VOP3P)
__device__ __forceinline__ unsigned pk_fma(unsigned a, unsigned b, unsigned c) {
    unsigned d;
    asm("v_pk_fma_f16 %0, %1, %2, %3" : "=v"(d) : "v"(a), "v"(b), "v"(c));
    return d;
}
__device__ __forceinline__ unsigned pk_mul(unsigned a, unsigned b) {
    unsigned d;
    asm("v_pk_mul_f16 %0, %1, %2" : "=v"(d) : "v"(a), "v"(b));
    return d;
}
__device__ __forceinline__ unsigned pk_max(unsigned a, unsigned b) {
    unsigned d;
    asm("v_pk_max_f16 %0, %1, %2" : "=v"(d) : "v"(a), "v"(b));
    return d;
}

// ---------------- CSR build kernels ----------------

__global__ void k_count(const int* __restrict__ dst, int* __restrict__ cnt, int E) {
    int i = blockIdx.x * 256 + threadIdx.x;
    if (i < E) atomicAdd(&cnt[dst[i]], 1);
}

__global__ void k_scan1(const int* __restrict__ cnt, int* __restrict__ partial, int N) {
    __shared__ int sm[256];
    int idx = blockIdx.x * 256 + threadIdx.x;
    sm[threadIdx.x] = (idx < N) ? cnt[idx] : 0;
    __syncthreads();
    for (int s = 128; s > 0; s >>= 1) {
        if (threadIdx.x < s) sm[threadIdx.x] += sm[threadIdx.x + s];
        __syncthreads();
    }
    if (threadIdx.x == 0) partial[blockIdx.x] = sm[0];
}

__global__ void k_scan2(int* __restrict__ partial, int nb) {
    __shared__ int sm[512];
    int t = threadIdx.x;
    sm[t] = (t < nb) ? partial[t] : 0;
    __syncthreads();
    for (int off = 1; off < 512; off <<= 1) {
        int v = (t >= off) ? sm[t - off] : 0;
        __syncthreads();
        sm[t] += v;
        __syncthreads();
    }
    if (t < nb) partial[t] = (t == 0) ? 0 : sm[t - 1];  // exclusive
}

__global__ void k_scan3(const int* __restrict__ cnt, const int* __restrict__ partial,
                        int* __restrict__ row_off, int* __restrict__ cursor,
                        float* __restrict__ invdeg, int N, int E) {
    __shared__ int sm[256];
    int idx = blockIdx.x * 256 + threadIdx.x;
    int v = (idx < N) ? cnt[idx] : 0;
    sm[threadIdx.x] = v;
    __syncthreads();
    for (int off = 1; off < 256; off <<= 1) {
        int u = (threadIdx.x >= off) ? sm[threadIdx.x - off] : 0;
        __syncthreads();
        sm[threadIdx.x] += u;
        __syncthreads();
    }
    if (idx < N) {
        int excl = partial[blockIdx.x] + sm[threadIdx.x] - v;
        row_off[idx] = excl;
        cursor[idx] = excl;
        invdeg[idx] = 1.0f / (float)((v > 1) ? v : 1);
    }
    if (idx == 0) row_off[N] = E;
}

// scatter edge payload into CSR slots: {src, si_h2, di_h2, rv_h2} (broadcast half2)
__global__ void k_scatter(const int* __restrict__ dst, const int* __restrict__ src,
                          const float* __restrict__ sidx, const float* __restrict__ didx,
                          const float* __restrict__ rev,
                          int* __restrict__ cursor, int4* __restrict__ payload, int E) {
    int i = blockIdx.x * 256 + threadIdx.x;
    if (i < E) {
        int p = atomicAdd(&cursor[dst[i]], 1);
        unsigned hs = (unsigned)__half_as_ushort(__float2half_rn(sidx[i]));
        unsigned hd = (unsigned)__half_as_ushort(__float2half_rn(didx[i]));
        unsigned hr = (unsigned)__half_as_ushort(__float2half_rn(rev[i]));
        int4 v;
        v.x = src[i];
        v.y = (int)(hs * 0x10001u);
        v.z = (int)(hd * 0x10001u);
        v.w = (int)(hr * 0x10001u);
        payload[p] = v;
    }
}

// ---------------- layer-1 tables: T0 = bf16(emb) [64][64], T1 = emb @ W1a^T fp16 [64][128] ----------------
// 64 blocks (one per gate type) x 128 threads (one per output col); emb row in LDS.

__global__ void k_tab(const float* __restrict__ emb, const float* __restrict__ w1,
                      u16* __restrict__ T0, u16* __restrict__ T1) {
    __shared__ float er[64];
    const int ty = blockIdx.x;
    const int j = threadIdx.x;
    if (j < 64) {
        float e = emb[ty * 64 + j];
        er[j] = e;
        T0[ty * 64 + j] = f2bf(e);
    }
    __syncthreads();
    float acc = 0.f;
#pragma unroll 16
    for (int k = 0; k < 64; k++)
        acc = fmaf(er[k], w1[j * 67 + k], acc);
    T1[ty * 128 + j] = (u16)__half_as_ushort(__float2half_rn(acc));
}

// gather tables per node: h0 (bf16, 8 uint4) + g (fp16, 16 uint4), coalesced row copies
__global__ void k_emb2(const int* __restrict__ gt, const uint4* __restrict__ T0,
                       const uint4* __restrict__ T1, uint4* __restrict__ h0,
                       uint4* __restrict__ g, int N) {
    int i = blockIdx.x * 256 + threadIdx.x;
    if (i < N * 16) {
        int n = i >> 4, c = i & 15;
        int ty = gt[n];
        g[i] = T1[ty * 16 + c];
        if (c < 8) h0[n * 8 + c] = T0[ty * 8 + c];
    }
}

// ---------------- weight fp32 -> bf16 dense conversion ----------------

struct WDesc {
    const float* src[10];
    u16* dst[10];
    int scols[10];
    int dcols[10];
    int n[10];
};

__global__ void k_wconv(WDesc d) {
    int seg = blockIdx.y;
    int idx = blockIdx.x * 256 + threadIdx.x;
    if (idx < d.n[seg]) {
        int dc = d.dcols[seg];
        int r = idx / dc, c = idx % dc;
        d.dst[seg][idx] = f2bf(d.src[seg][r * d.scols[seg] + c]);
    }
}

// edge-weight cols of W1 as half2 pairs: W1h[c][j] = half2(W1[2j][fi+c], W1[2j+1][fi+c])
struct EDesc {
    const float* src[5];
    unsigned* dst[5];
    int ldw[5];
    int fi[5];
};

__global__ void k_wedge(EDesc d) {
    int l = blockIdx.x;
    int i = threadIdx.x;
    if (i < 192) {
        int c = i >> 6, j = i & 63;
        float a = d.src[l][(size_t)(2 * j) * d.ldw[l] + d.fi[l] + c];
        float b = d.src[l][(size_t)(2 * j + 1) * d.ldw[l] + d.fi[l] + c];
        unsigned lo = (unsigned)__half_as_ushort(__float2half_rn(a));
        unsigned hi = (unsigned)__half_as_ushort(__float2half_rn(b));
        d.dst[l][(c << 6) + j] = lo | (hi << 16);
    }
}

// ---------------- edge aggregation: grid-stride chunked waves, packed fp16 MLP ----------------
// (round-8 structure — fastest measured; rounds 4/5/12 restructures all regressed)

__global__ __launch_bounds__(256)
void k_edge(int N,
            const int* __restrict__ row_off, const int4* __restrict__ payload,
            const u16* __restrict__ g,        // [N,128] fp16
            const unsigned* __restrict__ W1h, // [3][64] half2 pairs
            const float* __restrict__ invdeg,
            u16* __restrict__ hN)             // [N,128] bf16
{
    const int t = threadIdx.x;
    const int lane = t & 63;
    const int fl = lane & 15;
    const int eg = lane >> 4;
    const int wid = blockIdx.x * (blockDim.x >> 6) + (t >> 6);
    const int nwtot = gridDim.x * (blockDim.x >> 6);
    const int per = (N + nwtot - 1) / nwtot;
    const int n0 = wid * per;
    if (n0 >= N) return;
    const int n1 = (n0 + per < N) ? (n0 + per) : N;

    const uint4 wa = *(const uint4*)&W1h[(fl << 2)];
    const uint4 wb = *(const uint4*)&W1h[64 + (fl << 2)];
    const uint4 wc = *(const uint4*)&W1h[128 + (fl << 2)];
    const unsigned c001 = ((unsigned)__half_as_ushort(__float2half_rn(0.01f))) * 0x10001u;

    int beg = row_off[n0];
    for (int n = n0; n < n1; ++n) {
        const int end = row_off[n + 1];
        float acc[8] = {0.f, 0.f, 0.f, 0.f, 0.f, 0.f, 0.f, 0.f};

        int p = beg + eg;
        int4 pl;
        if (p < end) pl = payload[p];
        while (p < end) {
            const int pn = p + 4;
            int4 plN = pl;
            if (pn < end) plN = payload[pn];
            const uint4 gv = *(const uint4*)(g + ((size_t)pl.x << 7) + (fl << 3));
            const unsigned si = (unsigned)pl.y;
            const unsigned di = (unsigned)pl.z;
            const unsigned rv = (unsigned)pl.w;
            unsigned v0 = pk_fma(wa.x, si, gv.x);
            unsigned v1 = pk_fma(wa.y, si, gv.y);
            unsigned v2 = pk_fma(wa.z, si, gv.z);
            unsigned v3 = pk_fma(wa.w, si, gv.w);
            v0 = pk_fma(wb.x, di, v0);
            v1 = pk_fma(wb.y, di, v1);
            v2 = pk_fma(wb.z, di, v2);
            v3 = pk_fma(wb.w, di, v3);
            v0 = pk_fma(wc.x, rv, v0);
            v1 = pk_fma(wc.y, rv, v1);
            v2 = pk_fma(wc.z, rv, v2);
            v3 = pk_fma(wc.w, rv, v3);
            v0 = pk_max(v0, pk_mul(v0, c001));
            v1 = pk_max(v1, pk_mul(v1, c001));
            v2 = pk_max(v2, pk_mul(v2, c001));
            v3 = pk_max(v3, pk_mul(v3, c001));
            const float2 f0 = __half22float2(*(const __half2*)&v0);
            const float2 f1 = __half22float2(*(const __half2*)&v1);
            const float2 f2 = __half22float2(*(const __half2*)&v2);
            const float2 f3 = __half22float2(*(const __half2*)&v3);
            acc[0] += f0.x; acc[1] += f0.y;
            acc[2] += f1.x; acc[3] += f1.y;
            acc[4] += f2.x; acc[5] += f2.y;
            acc[6] += f3.x; acc[7] += f3.y;
            p = pn;
            pl = plN;
        }

#pragma unroll
        for (int r = 0; r < 8; r++) {
            acc[r] += __shfl_xor(acc[r], 16, 64);
            acc[r] += __shfl_xor(acc[r], 32, 64);
        }

        if (eg == 0) {
            const float inv = invdeg[n];
            unsigned q0 = (unsigned)f2bf(acc[0] * inv) | ((unsigned)f2bf(acc[1] * inv) << 16);
            unsigned q1 = (unsigned)f2bf(acc[2] * inv) | ((unsigned)f2bf(acc[3] * inv) << 16);
            unsigned q2 = (unsigned)f2bf(acc[4] * inv) | ((unsigned)f2bf(acc[5] * inv) << 16);
            unsigned q3 = (unsigned)f2bf(acc[6] * inv) | ((unsigned)f2bf(acc[7] * inv) << 16);
            uint4 out = make_uint4(q0, q1, q2, q3);
            *(uint4*)(hN + ((size_t)n << 7) + (fl << 3)) = out;
        }
        beg = end;
    }
}

// ---------------- bf16 MFMA GEMM, 512 threads = 8 waves (4M x 2N), staged LDS ----------------
// C[M,O] = [A1|A2] @ W[O,K]^T (+bias, act). Per wave: 32 rows x O/2 cols.
// FUSE: phase 2 computes g = h' @ Wg^T; h' re-read from GLOBAL (own block's L2-hot rows),
//       Wg re-staged into the dead Wlds region. OUTDT: 0=fp32, 1=bf16, 2=fp16.

template<int K, int O, int SPLIT, int BIAS, int RELU, int OUTDT, int FUSE>
__global__ __launch_bounds__(512, 4)
void k_gemm(int M,
            const u16* __restrict__ A1, int lda1,
            const u16* __restrict__ A2, int lda2,
            const u16* __restrict__ W,      // [O][K] bf16 dense
            const float* __restrict__ bias,
            void* __restrict__ Cout, int ldc,
            const u16* __restrict__ Wg,     // FUSE: next W1a [128][128] bf16
            u16* __restrict__ Gout)         // FUSE: g fp16 [M][128]
{
    constexpr int KP = K + 8;
    constexpr int HP = 136;
    constexpr int NF = O / 32;     // N-frags per wave (cols/wave = O/2)
    constexpr int WC = O / 2;
    __shared__ __align__(16) u16 Wlds[O * KP];       // phase1 W2; FUSE phase2: Wg at stride HP
    __shared__ __align__(16) u16 Atile[128 * 32];

    const int t = threadIdx.x;
    const int m0 = blockIdx.x * 128;
    const int w = t >> 6, l = t & 63;
    const int wm = w & 3, wn = w >> 2;
    const int lr = l & 15, lh = l >> 4;

    // stage W2 (L2-resident)
    for (int idx = t; idx < O * (K / 8); idx += 512) {
        int row = idx / (K / 8), ch = idx % (K / 8);
        uint4 v = *(const uint4*)(W + (size_t)row * K + ch * 8);
        *(uint4*)(&Wlds[row * KP + ch * 8]) = v;
    }

    f32x4 acc[2][NF];
#pragma unroll
    for (int mi = 0; mi < 2; mi++)
#pragma unroll
        for (int ni = 0; ni < NF; ni++) acc[mi][ni] = (f32x4){0.f, 0.f, 0.f, 0.f};

    __syncthreads();

    for (int kt = 0; kt < K / 32; ++kt) {
        const int k0 = kt * 32;
        const u16* Asrc;
        int lda, kof;
        if (k0 < SPLIT) { Asrc = A1; lda = lda1; kof = k0; }
        else            { Asrc = A2; lda = lda2; kof = k0 - SPLIT; }
        {
            int o = t * 16;                  // byte offset in Atile (512*16 = 8192)
            int row = o >> 6;
            int m = m0 + row;
            m = (m < M) ? m : (M - 1);
            gload_lds16(Asrc + (size_t)m * lda + kof + ((t & 3) << 3), (void*)(Atile + (o >> 1)));
        }
        __syncthreads();

        short8 a[2], b[NF];
#pragma unroll
        for (int mi = 0; mi < 2; mi++)
            a[mi] = *(const short8*)(Atile + (wm * 32 + mi * 16 + lr) * 32 + lh * 8);
#pragma unroll
        for (int ni = 0; ni < NF; ni++)
            b[ni] = *(const short8*)(Wlds + (size_t)(wn * WC + ni * 16 + lr) * KP + k0 + lh * 8);
#pragma unroll
        for (int mi = 0; mi < 2; mi++)
#pragma unroll
            for (int ni = 0; ni < NF; ni++)
                acc[mi][ni] = __builtin_amdgcn_mfma_f32_16x16x32_bf16(a[mi], b[ni], acc[mi][ni], 0, 0, 0);
        __syncthreads();
    }

    // FUSE: re-stage Wg into Wlds (dead after K-loop); overlaps epilogue VALU
    if (FUSE) {
        for (int idx = t; idx < 128 * 16; idx += 512) {
            int row = idx >> 4, ch = idx & 15;
            uint4 v = *(const uint4*)(Wg + (size_t)row * 128 + ch * 8);
            *(uint4*)(&Wlds[row * HP + ch * 8]) = v;
        }
    }

    // phase-1 epilogue (C/D map: row = lh*4 + i, col = lr per frag)
    float bv[NF];
#pragma unroll
    for (int ni = 0; ni < NF; ni++)
        bv[ni] = BIAS ? bias[wn * WC + ni * 16 + lr] : 0.f;
#pragma unroll
    for (int mi = 0; mi < 2; mi++) {
#pragma unroll
        for (int i = 0; i < 4; i++) {
            int row = m0 + wm * 32 + mi * 16 + lh * 4 + i;
            if (row < M) {
#pragma unroll
                for (int ni = 0; ni < NF; ni++) {
                    float v = acc[mi][ni][i] + bv[ni];
                    if (RELU) v = fmaxf(v, 0.f);
                    int col = wn * WC + ni * 16 + lr;
                    if (FUSE || OUTDT == 1) ((u16*)Cout)[(size_t)row * ldc + col] = f2bf(v);
                    else if (OUTDT == 2)    ((__half*)Cout)[(size_t)row * ldc + col] = __float2half(v);
                    else                    ((float*)Cout)[(size_t)row * ldc + col] = v;
                }
            }
        }
    }

    if (FUSE) {
        __syncthreads();   // drains vmcnt(0): h' stores visible in L2; Wg ds_writes done

        const u16* H = (const u16*)Cout;
        int hrow[2];
#pragma unroll
        for (int mi = 0; mi < 2; mi++) {
            int m = m0 + wm * 32 + mi * 16 + lr;
            hrow[mi] = (m < M) ? m : (M - 1);
        }

        f32x4 acc2[2][4];
#pragma unroll
        for (int mi = 0; mi < 2; mi++)
#pragma unroll
            for (int ni = 0; ni < 4; ni++) acc2[mi][ni] = (f32x4){0.f, 0.f, 0.f, 0.f};

#pragma unroll
        for (int kt = 0; kt < 4; ++kt) {
            const int k0 = kt * 32;
            short8 a[2], b[4];
#pragma unroll
            for (int mi = 0; mi < 2; mi++)
                a[mi] = *(const short8*)(H + (size_t)hrow[mi] * ldc + k0 + lh * 8);
#pragma unroll
            for (int ni = 0; ni < 4; ni++)
                b[ni] = *(const short8*)(Wlds + (size_t)(wn * 64 + ni * 16 + lr) * HP + k0 + lh * 8);
#pragma unroll
            for (int mi = 0; mi < 2; mi++)
#pragma unroll
                for (int ni = 0; ni < 4; ni++)
                    acc2[mi][ni] = __builtin_amdgcn_mfma_f32_16x16x32_bf16(a[mi], b[ni], acc2[mi][ni], 0, 0, 0);
        }

#pragma unroll
        for (int mi = 0; mi < 2; mi++) {
#pragma unroll
            for (int i = 0; i < 4; i++) {
                int row = m0 + wm * 32 + mi * 16 + lh * 4 + i;
                if (row < M) {
#pragma unroll
                    for (int ni = 0; ni < 4; ni++) {
                        int col = wn * 64 + ni * 16 + lr;
                        ((__half*)Gout)[(size_t)row * 128 + col] = __float2half(acc2[mi][ni][i]);
                    }
                }
            }
        }
    }
}

// ---------------- launcher ----------------

extern "C" void kernel_launch(void* const* d_in, const int* in_sizes, int n_in,
                              void* d_out, int out_size, void* d_ws, size_t ws_size,
                              hipStream_t stream)
{
    const int N = in_sizes[0];
    const int E = in_sizes[1];
    const int* gate = (const int*)d_in[0];
    const int* src = (const int*)d_in[1];
    const int* dst = (const int*)d_in[2];
    const float* sidx = (const float*)d_in[3];
    const float* didx = (const float*)d_in[4];
    const float* rev = (const float*)d_in[5];
    const float* emb = (const float*)d_in[6];
    const float* w1[5] = {(const float*)d_in[7], (const float*)d_in[10], (const float*)d_in[13],
                          (const float*)d_in[16], (const float*)d_in[19]};
    const float* w2[5] = {(const float*)d_in[8], (const float*)d_in[11], (const float*)d_in[14],
                          (const float*)d_in[17], (const float*)d_in[20]};
    const float* b2[5] = {(const float*)d_in[9], (const float*)d_in[12], (const float*)d_in[15],
                          (const float*)d_in[18], (const float*)d_in[21]};

    char* ws = (char*)d_ws;
    size_t off = 0;
    auto alloc = [&](size_t bytes) {
        void* p = ws + off;
        off = (off + bytes + 255) & ~(size_t)255;
        return p;
    };
    u16* hb0 = (u16*)alloc((size_t)N * 128 * 2);
    u16* hb1 = (u16*)alloc((size_t)N * 128 * 2);
    u16* hN = (u16*)alloc((size_t)N * 128 * 2);
    u16* g = (u16*)alloc((size_t)N * 128 * 2);        // fp16
    int* cnt = (int*)alloc((size_t)N * 4);
    int* row_off = (int*)alloc((size_t)(N + 1) * 4);
    int* cursor = (int*)alloc((size_t)N * 4);
    int4* payload = (int4*)alloc((size_t)E * 16);
    int* partial = (int*)alloc(512 * 4);
    float* invd = (float*)alloc((size_t)N * 4);
    unsigned* w1h = (unsigned*)alloc(5 * 192 * 4);
    u16* T0 = (u16*)alloc(64 * 64 * 2);
    u16* T1 = (u16*)alloc(64 * 128 * 2);
    u16* w1b[5];
    u16* w2b[5];
    const int fis[5] = {64, 128, 128, 128, 128};
    for (int i = 0; i < 5; i++) w1b[i] = (u16*)alloc((size_t)128 * fis[i] * 2);
    for (int i = 0; i < 5; i++) {
        int fo = (i == 4) ? 64 : 128;
        w2b[i] = (u16*)alloc((size_t)fo * (fis[i] + 128) * 2);
    }

    WDesc wd;
    for (int i = 0; i < 5; i++) {
        wd.src[i] = w1[i]; wd.dst[i] = w1b[i];
        wd.scols[i] = fis[i] + 3; wd.dcols[i] = fis[i]; wd.n[i] = 128 * fis[i];
        int fo = (i == 4) ? 64 : 128;
        wd.src[5 + i] = w2[i]; wd.dst[5 + i] = w2b[i];
        wd.scols[5 + i] = fis[i] + 128; wd.dcols[5 + i] = fis[i] + 128;
        wd.n[5 + i] = fo * (fis[i] + 128);
    }
    k_wconv<<<dim3(128, 10), dim3(256), 0, stream>>>(wd);

    EDesc ed;
    for (int i = 0; i < 5; i++) {
        ed.src[i] = w1[i];
        ed.dst[i] = w1h + i * 192;
        ed.ldw[i] = fis[i] + 3;
        ed.fi[i] = fis[i];
    }
    k_wedge<<<dim3(5), dim3(192), 0, stream>>>(ed);
    k_tab<<<dim3(64), dim3(128), 0, stream>>>(emb, w1[0], T0, T1);

    hipMemsetAsync(cnt, 0, (size_t)N * 4, stream);
    k_count<<<dim3((E + 255) / 256), dim3(256), 0, stream>>>(dst, cnt, E);
    const int nb = (N + 255) / 256;
    k_scan1<<<dim3(nb), dim3(256), 0, stream>>>(cnt, partial, N);
    k_scan2<<<dim3(1), dim3(512), 0, stream>>>(partial, nb);
    k_scan3<<<dim3(nb), dim3(256), 0, stream>>>(cnt, partial, row_off, cursor, invd, N, E);
    k_scatter<<<dim3((E + 255) / 256), dim3(256), 0, stream>>>(dst, src, sidx, didx, rev, cursor, payload, E);
    // layer-1 h0 + g via table gather (replaces k_emb + standalone g1 GEMM)
    k_emb2<<<dim3((N * 16 + 255) / 256), dim3(256), 0, stream>>>(
        gate, (const uint4*)T0, (const uint4*)T1, (uint4*)hb0, (uint4*)g, N);

    const int gg = (N + 127) / 128;
    const int eb = 2048;

    // ---- layer 1 (fi=64): edge + fused W2+g2 ----
    k_edge<<<dim3(eb), dim3(256), 0, stream>>>(N, row_off, payload, g, w1h + 0 * 192, invd, hN);
    k_gemm<192, 128, 64, 1, 1, 1, 1><<<dim3(gg), dim3(512), 0, stream>>>(
        N, hb0, 64, hN, 128, w2b[0], b2[0], hb1, 128, w1b[1], g);

    // ---- layers 2..4: fused W2 + next g ----
    u16* hcur = hb1;
    u16* hnxt = hb0;
    for (int l = 1; l < 4; ++l) {
        k_edge<<<dim3(eb), dim3(256), 0, stream>>>(N, row_off, payload, g, w1h + l * 192, invd, hN);
        k_gemm<256, 128, 128, 1, 1, 1, 1><<<dim3(gg), dim3(512), 0, stream>>>(
            N, hcur, 128, hN, 128, w2b[l], b2[l], hnxt, 128, w1b[l + 1], g);
        u16* tmp = hcur; hcur = hnxt; hnxt = tmp;
    }

    // ---- layer 5: edge + final W2 (out 64 fp32, no relu) ----
    k_edge<<<dim3(eb), dim3(256), 0, stream>>>(N, row_off, payload, g, w1h + 4 * 192, invd, hN);
    k_gemm<256, 64, 128, 1, 0, 0, 0><<<dim3(gg), dim3(512), 0, stream>>>(
        N, hcur, 128, hN, 128, w2b[4], b2[4], (float*)d_out, 64,
        (const u16*)nullptr, (u16*)nullptr);
}

// Round 15
// 391.370 us; speedup vs baseline: 1.1530x; 1.0230x over previous
//
#include <hip/hip_runtime.h>
#include <hip/hip_fp16.h>

typedef __attribute__((ext_vector_type(8))) short short8;
typedef __attribute__((ext_vector_type(4))) float f32x4;
typedef unsigned short u16;

__device__ __forceinline__ u16 f2bf(float f) {
    unsigned u = __float_as_uint(f);
    unsigned r = ((u >> 16) & 1) + 0x7FFFu;
    return (u16)((u + r) >> 16);
}

__device__ __forceinline__ void gload_lds16(const void* g, void* l) {
    __builtin_amdgcn_global_load_lds((const __attribute__((address_space(1))) unsigned int*)g,
                                     (__attribute__((address_space(3))) unsigned int*)l,
                                     16, 0, 0);
}

// packed fp16 ops (VOP3P)
__device__ __forceinline__ unsigned pk_fma(unsigned a, unsigned b, unsigned c) {
    unsigned d;
    asm("v_pk_fma_f16 %0, %1, %2, %3" : "=v"(d) : "v"(a), "v"(b), "v"(c));
    return d;
}
__device__ __forceinline__ unsigned pk_mul(unsigned a, unsigned b) {
    unsigned d;
    asm("v_pk_mul_f16 %0, %1, %2" : "=v"(d) : "v"(a), "v"(b));
    return d;
}
__device__ __forceinline__ unsigned pk_max(unsigned a, unsigned b) {
    unsigned d;
    asm("v_pk_max_f16 %0, %1, %2" : "=v"(d) : "v"(a), "v"(b));
    return d;
}
__device__ __forceinline__ unsigned pk_add(unsigned a, unsigned b) {
    unsigned d;
    asm("v_pk_add_f16 %0, %1, %2" : "=v"(d) : "v"(a), "v"(b));
    return d;
}

// ---------------- CSR build kernels ----------------

__global__ void k_count(const int* __restrict__ dst, int* __restrict__ cnt, int E) {
    int i = blockIdx.x * 256 + threadIdx.x;
    if (i < E) atomicAdd(&cnt[dst[i]], 1);
}

__global__ void k_scan1(const int* __restrict__ cnt, int* __restrict__ partial, int N) {
    __shared__ int sm[256];
    int idx = blockIdx.x * 256 + threadIdx.x;
    sm[threadIdx.x] = (idx < N) ? cnt[idx] : 0;
    __syncthreads();
    for (int s = 128; s > 0; s >>= 1) {
        if (threadIdx.x < s) sm[threadIdx.x] += sm[threadIdx.x + s];
        __syncthreads();
    }
    if (threadIdx.x == 0) partial[blockIdx.x] = sm[0];
}

__global__ void k_scan2(int* __restrict__ partial, int nb) {
    __shared__ int sm[512];
    int t = threadIdx.x;
    sm[t] = (t < nb) ? partial[t] : 0;
    __syncthreads();
    for (int off = 1; off < 512; off <<= 1) {
        int v = (t >= off) ? sm[t - off] : 0;
        __syncthreads();
        sm[t] += v;
        __syncthreads();
    }
    if (t < nb) partial[t] = (t == 0) ? 0 : sm[t - 1];  // exclusive
}

__global__ void k_scan3(const int* __restrict__ cnt, const int* __restrict__ partial,
                        int* __restrict__ row_off, int* __restrict__ cursor,
                        float* __restrict__ invdeg, int N, int E) {
    __shared__ int sm[256];
    int idx = blockIdx.x * 256 + threadIdx.x;
    int v = (idx < N) ? cnt[idx] : 0;
    sm[threadIdx.x] = v;
    __syncthreads();
    for (int off = 1; off < 256; off <<= 1) {
        int u = (threadIdx.x >= off) ? sm[threadIdx.x - off] : 0;
        __syncthreads();
        sm[threadIdx.x] += u;
        __syncthreads();
    }
    if (idx < N) {
        int excl = partial[blockIdx.x] + sm[threadIdx.x] - v;
        row_off[idx] = excl;
        cursor[idx] = excl;
        invdeg[idx] = 1.0f / (float)((v > 1) ? v : 1);
    }
    if (idx == 0) row_off[N] = E;
}

// scatter edge payload into CSR slots: {src, si_h2, di_h2, rv_h2} (broadcast half2)
__global__ void k_scatter(const int* __restrict__ dst, const int* __restrict__ src,
                          const float* __restrict__ sidx, const float* __restrict__ didx,
                          const float* __restrict__ rev,
                          int* __restrict__ cursor, int4* __restrict__ payload, int E) {
    int i = blockIdx.x * 256 + threadIdx.x;
    if (i < E) {
        int p = atomicAdd(&cursor[dst[i]], 1);
        unsigned hs = (unsigned)__half_as_ushort(__float2half_rn(sidx[i]));
        unsigned hd = (unsigned)__half_as_ushort(__float2half_rn(didx[i]));
        unsigned hr = (unsigned)__half_as_ushort(__float2half_rn(rev[i]));
        int4 v;
        v.x = src[i];
        v.y = (int)(hs * 0x10001u);
        v.z = (int)(hd * 0x10001u);
        v.w = (int)(hr * 0x10001u);
        payload[p] = v;
    }
}

// ---------------- layer-1 tables: T0 = bf16(emb) [64][64], T1 = emb @ W1a^T fp16 [64][128] ----------------
// 64 blocks (one per gate type) x 128 threads (one per output col); emb row in LDS.

__global__ void k_tab(const float* __restrict__ emb, const float* __restrict__ w1,
                      u16* __restrict__ T0, u16* __restrict__ T1) {
    __shared__ float er[64];
    const int ty = blockIdx.x;
    const int j = threadIdx.x;
    if (j < 64) {
        float e = emb[ty * 64 + j];
        er[j] = e;
        T0[ty * 64 + j] = f2bf(e);
    }
    __syncthreads();
    float acc = 0.f;
#pragma unroll 16
    for (int k = 0; k < 64; k++)
        acc = fmaf(er[k], w1[j * 67 + k], acc);
    T1[ty * 128 + j] = (u16)__half_as_ushort(__float2half_rn(acc));
}

// gather tables per node: h0 (bf16, 8 uint4) + g (fp16, 16 uint4), coalesced row copies
__global__ void k_emb2(const int* __restrict__ gt, const uint4* __restrict__ T0,
                       const uint4* __restrict__ T1, uint4* __restrict__ h0,
                       uint4* __restrict__ g, int N) {
    int i = blockIdx.x * 256 + threadIdx.x;
    if (i < N * 16) {
        int n = i >> 4, c = i & 15;
        int ty = gt[n];
        g[i] = T1[ty * 16 + c];
        if (c < 8) h0[n * 8 + c] = T0[ty * 8 + c];
    }
}

// ---------------- weight fp32 -> bf16 dense conversion ----------------

struct WDesc {
    const float* src[10];
    u16* dst[10];
    int scols[10];
    int dcols[10];
    int n[10];
};

__global__ void k_wconv(WDesc d) {
    int seg = blockIdx.y;
    int idx = blockIdx.x * 256 + threadIdx.x;
    if (idx < d.n[seg]) {
        int dc = d.dcols[seg];
        int r = idx / dc, c = idx % dc;
        d.dst[seg][idx] = f2bf(d.src[seg][r * d.scols[seg] + c]);
    }
}

// edge-weight cols of W1 as half2 pairs: W1h[c][j] = half2(W1[2j][fi+c], W1[2j+1][fi+c])
struct EDesc {
    const float* src[5];
    unsigned* dst[5];
    int ldw[5];
    int fi[5];
};

__global__ void k_wedge(EDesc d) {
    int l = blockIdx.x;
    int i = threadIdx.x;
    if (i < 192) {
        int c = i >> 6, j = i & 63;
        float a = d.src[l][(size_t)(2 * j) * d.ldw[l] + d.fi[l] + c];
        float b = d.src[l][(size_t)(2 * j + 1) * d.ldw[l] + d.fi[l] + c];
        unsigned lo = (unsigned)__half_as_ushort(__float2half_rn(a));
        unsigned hi = (unsigned)__half_as_ushort(__float2half_rn(b));
        d.dst[l][(c << 6) + j] = lo | (hi << 16);
    }
}

// ---------------- edge aggregation: round-8 chunked loop + pk-accum + depth-1 prefetch ----------------

__global__ __launch_bounds__(256)
void k_edge(int N,
            const int* __restrict__ row_off, const int4* __restrict__ payload,
            const u16* __restrict__ g,        // [N,128] fp16
            const unsigned* __restrict__ W1h, // [3][64] half2 pairs
            const float* __restrict__ invdeg,
            u16* __restrict__ hN)             // [N,128] bf16
{
    const int t = threadIdx.x;
    const int lane = t & 63;
    const int fl = lane & 15;
    const int eg = lane >> 4;
    const int wid = blockIdx.x * (blockDim.x >> 6) + (t >> 6);
    const int nwtot = gridDim.x * (blockDim.x >> 6);
    const int per = (N + nwtot - 1) / nwtot;
    const int n0 = wid * per;
    if (n0 >= N) return;
    const int n1 = (n0 + per < N) ? (n0 + per) : N;

    const uint4 wa = *(const uint4*)&W1h[(fl << 2)];
    const uint4 wb = *(const uint4*)&W1h[64 + (fl << 2)];
    const uint4 wc = *(const uint4*)&W1h[128 + (fl << 2)];
    const unsigned c001 = ((unsigned)__half_as_ushort(__float2half_rn(0.01f))) * 0x10001u;

    int beg = row_off[n0];
    for (int n = n0; n < n1; ++n) {
        const int end = row_off[n + 1];
        unsigned acc0 = 0u, acc1 = 0u, acc2 = 0u, acc3 = 0u;

        int p = beg + eg;
        if (p < end) {
            int4 pl = payload[p];
            uint4 gv = *(const uint4*)(g + ((size_t)pl.x << 7) + (fl << 3));
            for (;;) {
                const int pn = p + 4;
                // branchless clamped depth-1 prefetch (payload + gather)
                const int pc = (pn < end) ? pn : p;
                int4 plN = payload[pc];
                uint4 gvN = *(const uint4*)(g + ((size_t)plN.x << 7) + (fl << 3));

                const unsigned si = (unsigned)pl.y;
                const unsigned di = (unsigned)pl.z;
                const unsigned rv = (unsigned)pl.w;
                unsigned v0 = pk_fma(wa.x, si, gv.x);
                unsigned v1 = pk_fma(wa.y, si, gv.y);
                unsigned v2 = pk_fma(wa.z, si, gv.z);
                unsigned v3 = pk_fma(wa.w, si, gv.w);
                v0 = pk_fma(wb.x, di, v0);
                v1 = pk_fma(wb.y, di, v1);
                v2 = pk_fma(wb.z, di, v2);
                v3 = pk_fma(wb.w, di, v3);
                v0 = pk_fma(wc.x, rv, v0);
                v1 = pk_fma(wc.y, rv, v1);
                v2 = pk_fma(wc.z, rv, v2);
                v3 = pk_fma(wc.w, rv, v3);
                v0 = pk_max(v0, pk_mul(v0, c001));
                v1 = pk_max(v1, pk_mul(v1, c001));
                v2 = pk_max(v2, pk_mul(v2, c001));
                v3 = pk_max(v3, pk_mul(v3, c001));
                acc0 = pk_add(acc0, v0);
                acc1 = pk_add(acc1, v1);
                acc2 = pk_add(acc2, v2);
                acc3 = pk_add(acc3, v3);

                if (pn >= end) break;
                p = pn;
                pl = plN;
                gv = gvN;
            }
        }

        // cross-group reduce (packed fp16, 8 shfl)
        acc0 = pk_add(acc0, (unsigned)__shfl_xor((int)acc0, 16, 64));
        acc1 = pk_add(acc1, (unsigned)__shfl_xor((int)acc1, 16, 64));
        acc2 = pk_add(acc2, (unsigned)__shfl_xor((int)acc2, 16, 64));
        acc3 = pk_add(acc3, (unsigned)__shfl_xor((int)acc3, 16, 64));
        acc0 = pk_add(acc0, (unsigned)__shfl_xor((int)acc0, 32, 64));
        acc1 = pk_add(acc1, (unsigned)__shfl_xor((int)acc1, 32, 64));
        acc2 = pk_add(acc2, (unsigned)__shfl_xor((int)acc2, 32, 64));
        acc3 = pk_add(acc3, (unsigned)__shfl_xor((int)acc3, 32, 64));

        if (eg == 0) {
            const float inv = invdeg[n];
            const float2 f0 = __half22float2(*(const __half2*)&acc0);
            const float2 f1 = __half22float2(*(const __half2*)&acc1);
            const float2 f2 = __half22float2(*(const __half2*)&acc2);
            const float2 f3 = __half22float2(*(const __half2*)&acc3);
            unsigned q0 = (unsigned)f2bf(f0.x * inv) | ((unsigned)f2bf(f0.y * inv) << 16);
            unsigned q1 = (unsigned)f2bf(f1.x * inv) | ((unsigned)f2bf(f1.y * inv) << 16);
            unsigned q2 = (unsigned)f2bf(f2.x * inv) | ((unsigned)f2bf(f2.y * inv) << 16);
            unsigned q3 = (unsigned)f2bf(f3.x * inv) | ((unsigned)f2bf(f3.y * inv) << 16);
            uint4 out = make_uint4(q0, q1, q2, q3);
            *(uint4*)(hN + ((size_t)n << 7) + (fl << 3)) = out;
        }
        beg = end;
    }
}

// ---------------- bf16 MFMA GEMM, 512 threads = 8 waves (4M x 2N), staged LDS ----------------
// C[M,O] = [A1|A2] @ W[O,K]^T (+bias, act). Per wave: 32 rows x O/2 cols.
// FUSE: phase 2 computes g = h' @ Wg^T; h' re-read from GLOBAL (own block's L2-hot rows),
//       Wg re-staged into the dead Wlds region. OUTDT: 0=fp32, 1=bf16, 2=fp16.

template<int K, int O, int SPLIT, int BIAS, int RELU, int OUTDT, int FUSE>
__global__ __launch_bounds__(512, 4)
void k_gemm(int M,
            const u16* __restrict__ A1, int lda1,
            const u16* __restrict__ A2, int lda2,
            const u16* __restrict__ W,      // [O][K] bf16 dense
            const float* __restrict__ bias,
            void* __restrict__ Cout, int ldc,
            const u16* __restrict__ Wg,     // FUSE: next W1a [128][128] bf16
            u16* __restrict__ Gout)         // FUSE: g fp16 [M][128]
{
    constexpr int KP = K + 8;
    constexpr int HP = 136;
    constexpr int NF = O / 32;     // N-frags per wave (cols/wave = O/2)
    constexpr int WC = O / 2;
    __shared__ __align__(16) u16 Wlds[O * KP];       // phase1 W2; FUSE phase2: Wg at stride HP
    __shared__ __align__(16) u16 Atile[128 * 32];

    const int t = threadIdx.x;
    const int m0 = blockIdx.x * 128;
    const int w = t >> 6, l = t & 63;
    const int wm = w & 3, wn = w >> 2;
    const int lr = l & 15, lh = l >> 4;

    // stage W2 (L2-resident)
    for (int idx = t; idx < O * (K / 8); idx += 512) {
        int row = idx / (K / 8), ch = idx % (K / 8);
        uint4 v = *(const uint4*)(W + (size_t)row * K + ch * 8);
        *(uint4*)(&Wlds[row * KP + ch * 8]) = v;
    }

    f32x4 acc[2][NF];
#pragma unroll
    for (int mi = 0; mi < 2; mi++)
#pragma unroll
        for (int ni = 0; ni < NF; ni++) acc[mi][ni] = (f32x4){0.f, 0.f, 0.f, 0.f};

    __syncthreads();

    for (int kt = 0; kt < K / 32; ++kt) {
        const int k0 = kt * 32;
        const u16* Asrc;
        int lda, kof;
        if (k0 < SPLIT) { Asrc = A1; lda = lda1; kof = k0; }
        else            { Asrc = A2; lda = lda2; kof = k0 - SPLIT; }
        {
            int o = t * 16;                  // byte offset in Atile (512*16 = 8192)
            int row = o >> 6;
            int m = m0 + row;
            m = (m < M) ? m : (M - 1);
            gload_lds16(Asrc + (size_t)m * lda + kof + ((t & 3) << 3), (void*)(Atile + (o >> 1)));
        }
        __syncthreads();

        short8 a[2], b[NF];
#pragma unroll
        for (int mi = 0; mi < 2; mi++)
            a[mi] = *(const short8*)(Atile + (wm * 32 + mi * 16 + lr) * 32 + lh * 8);
#pragma unroll
        for (int ni = 0; ni < NF; ni++)
            b[ni] = *(const short8*)(Wlds + (size_t)(wn * WC + ni * 16 + lr) * KP + k0 + lh * 8);
#pragma unroll
        for (int mi = 0; mi < 2; mi++)
#pragma unroll
            for (int ni = 0; ni < NF; ni++)
                acc[mi][ni] = __builtin_amdgcn_mfma_f32_16x16x32_bf16(a[mi], b[ni], acc[mi][ni], 0, 0, 0);
        __syncthreads();
    }

    // FUSE: re-stage Wg into Wlds (dead after K-loop); overlaps epilogue VALU
    if (FUSE) {
        for (int idx = t; idx < 128 * 16; idx += 512) {
            int row = idx >> 4, ch = idx & 15;
            uint4 v = *(const uint4*)(Wg + (size_t)row * 128 + ch * 8);
            *(uint4*)(&Wlds[row * HP + ch * 8]) = v;
        }
    }

    // phase-1 epilogue (C/D map: row = lh*4 + i, col = lr per frag)
    float bv[NF];
#pragma unroll
    for (int ni = 0; ni < NF; ni++)
        bv[ni] = BIAS ? bias[wn * WC + ni * 16 + lr] : 0.f;
#pragma unroll
    for (int mi = 0; mi < 2; mi++) {
#pragma unroll
        for (int i = 0; i < 4; i++) {
            int row = m0 + wm * 32 + mi * 16 + lh * 4 + i;
            if (row < M) {
#pragma unroll
                for (int ni = 0; ni < NF; ni++) {
                    float v = acc[mi][ni][i] + bv[ni];
                    if (RELU) v = fmaxf(v, 0.f);
                    int col = wn * WC + ni * 16 + lr;
                    if (FUSE || OUTDT == 1) ((u16*)Cout)[(size_t)row * ldc + col] = f2bf(v);
                    else if (OUTDT == 2)    ((__half*)Cout)[(size_t)row * ldc + col] = __float2half(v);
                    else                    ((float*)Cout)[(size_t)row * ldc + col] = v;
                }
            }
        }
    }

    if (FUSE) {
        __syncthreads();   // drains vmcnt(0): h' stores visible in L2; Wg ds_writes done

        const u16* H = (const u16*)Cout;
        int hrow[2];
#pragma unroll
        for (int mi = 0; mi < 2; mi++) {
            int m = m0 + wm * 32 + mi * 16 + lr;
            hrow[mi] = (m < M) ? m : (M - 1);
        }

        f32x4 acc2[2][4];
#pragma unroll
        for (int mi = 0; mi < 2; mi++)
#pragma unroll
            for (int ni = 0; ni < 4; ni++) acc2[mi][ni] = (f32x4){0.f, 0.f, 0.f, 0.f};

#pragma unroll
        for (int kt = 0; kt < 4; ++kt) {
            const int k0 = kt * 32;
            short8 a[2], b[4];
#pragma unroll
            for (int mi = 0; mi < 2; mi++)
                a[mi] = *(const short8*)(H + (size_t)hrow[mi] * ldc + k0 + lh * 8);
#pragma unroll
            for (int ni = 0; ni < 4; ni++)
                b[ni] = *(const short8*)(Wlds + (size_t)(wn * 64 + ni * 16 + lr) * HP + k0 + lh * 8);
#pragma unroll
            for (int mi = 0; mi < 2; mi++)
#pragma unroll
                for (int ni = 0; ni < 4; ni++)
                    acc2[mi][ni] = __builtin_amdgcn_mfma_f32_16x16x32_bf16(a[mi], b[ni], acc2[mi][ni], 0, 0, 0);
        }

#pragma unroll
        for (int mi = 0; mi < 2; mi++) {
#pragma unroll
            for (int i = 0; i < 4; i++) {
                int row = m0 + wm * 32 + mi * 16 + lh * 4 + i;
                if (row < M) {
#pragma unroll
                    for (int ni = 0; ni < 4; ni++) {
                        int col = wn * 64 + ni * 16 + lr;
                        ((__half*)Gout)[(size_t)row * 128 + col] = __float2half(acc2[mi][ni][i]);
                    }
                }
            }
        }
    }
}

// ---------------- launcher ----------------

extern "C" void kernel_launch(void* const* d_in, const int* in_sizes, int n_in,
                              void* d_out, int out_size, void* d_ws, size_t ws_size,
                              hipStream_t stream)
{
    const int N = in_sizes[0];
    const int E = in_sizes[1];
    const int* gate = (const int*)d_in[0];
    const int* src = (const int*)d_in[1];
    const int* dst = (const int*)d_in[2];
    const float* sidx = (const float*)d_in[3];
    const float* didx = (const float*)d_in[4];
    const float* rev = (const float*)d_in[5];
    const float* emb = (const float*)d_in[6];
    const float* w1[5] = {(const float*)d_in[7], (const float*)d_in[10], (const float*)d_in[13],
                          (const float*)d_in[16], (const float*)d_in[19]};
    const float* w2[5] = {(const float*)d_in[8], (const float*)d_in[11], (const float*)d_in[14],
                          (const float*)d_in[17], (const float*)d_in[20]};
    const float* b2[5] = {(const float*)d_in[9], (const float*)d_in[12], (const float*)d_in[15],
                          (const float*)d_in[18], (const float*)d_in[21]};

    char* ws = (char*)d_ws;
    size_t off = 0;
    auto alloc = [&](size_t bytes) {
        void* p = ws + off;
        off = (off + bytes + 255) & ~(size_t)255;
        return p;
    };
    u16* hb0 = (u16*)alloc((size_t)N * 128 * 2);
    u16* hb1 = (u16*)alloc((size_t)N * 128 * 2);
    u16* hN = (u16*)alloc((size_t)N * 128 * 2);
    u16* g = (u16*)alloc((size_t)N * 128 * 2);        // fp16
    int* cnt = (int*)alloc((size_t)N * 4);
    int* row_off = (int*)alloc((size_t)(N + 1) * 4);
    int* cursor = (int*)alloc((size_t)N * 4);
    int4* payload = (int4*)alloc((size_t)E * 16);
    int* partial = (int*)alloc(512 * 4);
    float* invd = (float*)alloc((size_t)N * 4);
    unsigned* w1h = (unsigned*)alloc(5 * 192 * 4);
    u16* T0 = (u16*)alloc(64 * 64 * 2);
    u16* T1 = (u16*)alloc(64 * 128 * 2);
    u16* w1b[5];
    u16* w2b[5];
    const int fis[5] = {64, 128, 128, 128, 128};
    for (int i = 0; i < 5; i++) w1b[i] = (u16*)alloc((size_t)128 * fis[i] * 2);
    for (int i = 0; i < 5; i++) {
        int fo = (i == 4) ? 64 : 128;
        w2b[i] = (u16*)alloc((size_t)fo * (fis[i] + 128) * 2);
    }

    WDesc wd;
    for (int i = 0; i < 5; i++) {
        wd.src[i] = w1[i]; wd.dst[i] = w1b[i];
        wd.scols[i] = fis[i] + 3; wd.dcols[i] = fis[i]; wd.n[i] = 128 * fis[i];
        int fo = (i == 4) ? 64 : 128;
        wd.src[5 + i] = w2[i]; wd.dst[5 + i] = w2b[i];
        wd.scols[5 + i] = fis[i] + 128; wd.dcols[5 + i] = fis[i] + 128;
        wd.n[5 + i] = fo * (fis[i] + 128);
    }
    k_wconv<<<dim3(128, 10), dim3(256), 0, stream>>>(wd);

    EDesc ed;
    for (int i = 0; i < 5; i++) {
        ed.src[i] = w1[i];
        ed.dst[i] = w1h + i * 192;
        ed.ldw[i] = fis[i] + 3;
        ed.fi[i] = fis[i];
    }
    k_wedge<<<dim3(5), dim3(192), 0, stream>>>(ed);
    k_tab<<<dim3(64), dim3(128), 0, stream>>>(emb, w1[0], T0, T1);

    hipMemsetAsync(cnt, 0, (size_t)N * 4, stream);
    k_count<<<dim3((E + 255) / 256), dim3(256), 0, stream>>>(dst, cnt, E);
    const int nb = (N + 255) / 256;
    k_scan1<<<dim3(nb), dim3(256), 0, stream>>>(cnt, partial, N);
    k_scan2<<<dim3(1), dim3(512), 0, stream>>>(partial, nb);
    k_scan3<<<dim3(nb), dim3(256), 0, stream>>>(cnt, partial, row_off, cursor, invd, N, E);
    k_scatter<<<dim3((E + 255) / 256), dim3(256), 0, stream>>>(dst, src, sidx, didx, rev, cursor, payload, E);
    // layer-1 h0 + g via table gather (replaces k_emb + standalone g1 GEMM)
    k_emb2<<<dim3((N * 16 + 255) / 256), dim3(256), 0, stream>>>(
        gate, (const uint4*)T0, (const uint4*)T1, (uint4*)hb0, (uint4*)g, N);

    const int gg = (N + 127) / 128;
    const int eb = 2048;

    // ---- layer 1 (fi=64): edge + fused W2+g2 ----
    k_edge<<<dim3(eb), dim3(256), 0, stream>>>(N, row_off, payload, g, w1h + 0 * 192, invd, hN);
    k_gemm<192, 128, 64, 1, 1, 1, 1><<<dim3(gg), dim3(512), 0, stream>>>(
        N, hb0, 64, hN, 128, w2b[0], b2[0], hb1, 128, w1b[1], g);

    // ---- layers 2..4: fused W2 + next g ----
    u16* hcur = hb1;
    u16* hnxt = hb0;
    for (int l = 1; l < 4; ++l) {
        k_edge<<<dim3(eb), dim3(256), 0, stream>>>(N, row_off, payload, g, w1h + l * 192, invd, hN);
        k_gemm<256, 128, 128, 1, 1, 1, 1><<<dim3(gg), dim3(512), 0, stream>>>(
            N, hcur, 128, hN, 128, w2b[l], b2[l], hnxt, 128, w1b[l + 1], g);
        u16* tmp = hcur; hcur = hnxt; hnxt = tmp;
    }

    // ---- layer 5: edge + final W2 (out 64 fp32, no relu) ----
    k_edge<<<dim3(eb), dim3(256), 0, stream>>>(N, row_off, payload, g, w1h + 4 * 192, invd, hN);
    k_gemm<256, 64, 128, 1, 0, 0, 0><<<dim3(gg), dim3(512), 0, stream>>>(
        N, hcur, 128, hN, 128, w2b[4], b2[4], (float*)d_out, 64,
        (const u16*)nullptr, (u16*)nullptr);
}